// Round 1
// baseline (1080.548 us; speedup 1.0000x reference)
//
#include <hip/hip_runtime.h>
#include <math.h>

// ---------------------------------------------------------------------------
// GAT regression: 5x (GATConv -> ReLU -> BN) -> mean pool -> linear head.
// fp32 end-to-end. CSR-by-dst built on device each launch (deterministic work).
// ---------------------------------------------------------------------------

__global__ __launch_bounds__(256) void init_counts_kernel(int* __restrict__ counts, int N) {
    int i = blockIdx.x * blockDim.x + threadIdx.x;
    if (i < N) counts[i] = 1;  // self-loop contributes 1 in-edge per node
}

__global__ __launch_bounds__(256) void count_kernel(const int* __restrict__ edst,
                                                    int* __restrict__ counts, int E) {
    int i = blockIdx.x * blockDim.x + threadIdx.x;
    if (i < E) atomicAdd(&counts[edst[i]], 1);
}

// Single-block exclusive scan over N counts -> row_start[N+1]; also seeds cursor.
__global__ __launch_bounds__(1024) void scan_kernel(const int* __restrict__ counts,
                                                    int* __restrict__ row_start,
                                                    int* __restrict__ cursor, int N) {
    __shared__ int partial[1024];
    int t = threadIdx.x;
    int chunk = (N + 1023) >> 10;
    int b = t * chunk;
    int e = min(b + chunk, N);
    int s = 0;
    for (int i = b; i < e; ++i) s += counts[i];
    partial[t] = s;
    __syncthreads();
    for (int off = 1; off < 1024; off <<= 1) {
        int v = (t >= off) ? partial[t - off] : 0;
        __syncthreads();
        partial[t] += v;
        __syncthreads();
    }
    int pre = (t == 0) ? 0 : partial[t - 1];
    for (int i = b; i < e; ++i) {
        row_start[i] = pre;
        cursor[i] = pre;
        pre += counts[i];
    }
    if (t == 1023) row_start[N] = pre;  // == E + N
}

__global__ __launch_bounds__(256) void scatter_kernel(const int* __restrict__ esrc,
                                                      const int* __restrict__ edst,
                                                      int* __restrict__ cursor,
                                                      int* __restrict__ csr_src,
                                                      int E, int N) {
    int i = blockIdx.x * blockDim.x + threadIdx.x;
    int T = E + N;
    if (i >= T) return;
    int s, d;
    if (i < E) { s = esrc[i]; d = edst[i]; }
    else       { s = i - E;   d = s; }       // self loops appended after edges
    int pos = atomicAdd(&cursor[d], 1);
    csr_src[pos] = s;
}

// Layer 1: x is [N,1], W1 is [1,64] -> h[n][c] = X[n]*W1[c]; alpha dots collapse.
__global__ __launch_bounds__(256) void layer1_kernel(const float* __restrict__ X,
                                                     const float* __restrict__ W1,
                                                     const float* __restrict__ a_s,
                                                     const float* __restrict__ a_d,
                                                     float* __restrict__ h,
                                                     float* __restrict__ as,
                                                     float* __restrict__ ad, int N) {
    int lane = threadIdx.x & 63;
    int wave = threadIdx.x >> 6;
    int wpb  = blockDim.x >> 6;
    float w  = W1[lane];
    float da = w * a_s[lane];
    float db = w * a_d[lane];
#pragma unroll
    for (int o = 32; o > 0; o >>= 1) {
        da += __shfl_xor(da, o, 64);
        db += __shfl_xor(db, o, 64);
    }
    for (int n = blockIdx.x * wpb + wave; n < N; n += gridDim.x * wpb) {
        float xv = X[n];
        h[(size_t)n * 64 + lane] = xv * w;
        if (lane == 0) { as[n] = xv * da; ad[n] = xv * db; }
    }
}

// Layers 2..5 transform: h = x @ W ([64,64] in LDS), plus per-node alpha dots.
__global__ __launch_bounds__(256) void transform_kernel(const float* __restrict__ x,
                                                        const float* __restrict__ W,
                                                        const float* __restrict__ a_s,
                                                        const float* __restrict__ a_d,
                                                        float* __restrict__ h,
                                                        float* __restrict__ as,
                                                        float* __restrict__ ad, int N) {
    __shared__ float Wl[64 * 64];
    for (int i = threadIdx.x; i < 64 * 64; i += blockDim.x) Wl[i] = W[i];
    __syncthreads();
    int lane = threadIdx.x & 63;
    int wave = threadIdx.x >> 6;
    int wpb  = blockDim.x >> 6;
    float asc = a_s[lane], adc = a_d[lane];
    for (int n = blockIdx.x * wpb + wave; n < N; n += gridDim.x * wpb) {
        float xv  = x[(size_t)n * 64 + lane];
        float acc = 0.f;
#pragma unroll
        for (int k = 0; k < 64; ++k) {
            float xk = __shfl(xv, k, 64);
            acc = fmaf(xk, Wl[k * 64 + lane], acc);
        }
        h[(size_t)n * 64 + lane] = acc;
        float s1 = acc * asc, s2 = acc * adc;
#pragma unroll
        for (int o = 32; o > 0; o >>= 1) {
            s1 += __shfl_xor(s1, o, 64);
            s2 += __shfl_xor(s2, o, 64);
        }
        if (lane == 0) { as[n] = s1; ad[n] = s2; }
    }
}

// Per-dst-node softmax + weighted sum over in-edges; fused bias+ReLU+BN epilogue.
// One wave per node, lane = channel.
__global__ __launch_bounds__(256) void aggregate_kernel(const float* __restrict__ h,
                                                        const float* __restrict__ as,
                                                        const float* __restrict__ ad,
                                                        const int* __restrict__ row_start,
                                                        const int* __restrict__ csr_src,
                                                        const float* __restrict__ bias,
                                                        const float* __restrict__ gamma,
                                                        const float* __restrict__ beta,
                                                        const float* __restrict__ mean,
                                                        const float* __restrict__ var,
                                                        float* __restrict__ xout, int N) {
    int lane = threadIdx.x & 63;
    int wave = threadIdx.x >> 6;
    int wpb  = blockDim.x >> 6;
    float bc    = bias[lane];
    float scale = gamma[lane] * rsqrtf(var[lane] + 1e-5f);
    float shift = beta[lane] - mean[lane] * scale;
    for (int d = blockIdx.x * wpb + wave; d < N; d += gridDim.x * wpb) {
        int rs = row_start[d], re = row_start[d + 1];
        float add = ad[d];
        // pass 1: segment max (lanes parallel over edges)
        float m = -INFINITY;
        for (int j = rs + lane; j < re; j += 64) {
            int s   = csr_src[j];
            float e = as[s] + add;
            e = (e > 0.f) ? e : 0.2f * e;
            m = fmaxf(m, e);
        }
#pragma unroll
        for (int o = 32; o > 0; o >>= 1) m = fmaxf(m, __shfl_xor(m, o, 64));
        // pass 2: exp-sum + weighted gather of h[src]
        float z = 0.f, acc = 0.f;
        for (int j = rs; j < re; ++j) {
            int s   = csr_src[j];
            float e = as[s] + add;
            e = (e > 0.f) ? e : 0.2f * e;
            float w = __expf(e - m);
            z += w;
            acc = fmaf(h[(size_t)s * 64 + lane], w, acc);
        }
        float o = acc / z + bc;
        o = fmaxf(o, 0.f);                       // ReLU
        xout[(size_t)d * 64 + lane] = fmaf(o, scale, shift);  // BN (eval)
    }
}

__global__ __launch_bounds__(256) void gcount_kernel(const int* __restrict__ batch,
                                                     int* __restrict__ gcnt, int N) {
    int i = blockIdx.x * blockDim.x + threadIdx.x;
    if (i < N) atomicAdd(&gcnt[batch[i]], 1);
}

__global__ __launch_bounds__(256) void gscan_kernel(const int* __restrict__ gcnt,
                                                    int* __restrict__ gstart, int G) {
    __shared__ int buf[256];
    int t = threadIdx.x;
    buf[t] = (t < G) ? gcnt[t] : 0;
    __syncthreads();
    for (int off = 1; off < 256; off <<= 1) {
        int v = (t >= off) ? buf[t - off] : 0;
        __syncthreads();
        buf[t] += v;
        __syncthreads();
    }
    if (t < G) gstart[t] = buf[t] - gcnt[t];  // exclusive
}

// One wave per graph: mean pool (batch is sorted -> contiguous) + linear head.
__global__ __launch_bounds__(256) void pool_kernel(const float* __restrict__ x,
                                                   const int* __restrict__ gstart,
                                                   const int* __restrict__ gcnt,
                                                   const float* __restrict__ Wr,
                                                   const float* __restrict__ br,
                                                   float* __restrict__ out, int G) {
    int lane = threadIdx.x & 63;
    int wave = threadIdx.x >> 6;
    int wpb  = blockDim.x >> 6;
    for (int g = blockIdx.x * wpb + wave; g < G; g += gridDim.x * wpb) {
        int s = gstart[g], cnt = gcnt[g];
        float acc = 0.f;
        for (int n = s; n < s + cnt; ++n) acc += x[(size_t)n * 64 + lane];
        float pooled = acc / fmaxf((float)cnt, 1.f);
        out[G + (size_t)g * 64 + lane] = pooled;  // pooled section after pred[G]
        float p = pooled * Wr[lane];
#pragma unroll
        for (int o = 32; o > 0; o >>= 1) p += __shfl_xor(p, o, 64);
        if (lane == 0) out[g] = p + br[0];
    }
}

extern "C" void kernel_launch(void* const* d_in, const int* in_sizes, int n_in,
                              void* d_out, int out_size, void* d_ws, size_t ws_size,
                              hipStream_t stream) {
    const float* X        = (const float*)d_in[0];
    const int*   ei       = (const int*)d_in[1];
    const int*   batch    = (const int*)d_in[2];
    const float* W1       = (const float*)d_in[3];
    const float* Ws       = (const float*)d_in[4];
    const float* att_src  = (const float*)d_in[5];
    const float* att_dst  = (const float*)d_in[6];
    const float* bias     = (const float*)d_in[7];
    const float* bn_gamma = (const float*)d_in[8];
    const float* bn_beta  = (const float*)d_in[9];
    const float* bn_mean  = (const float*)d_in[10];
    const float* bn_var   = (const float*)d_in[11];
    const float* Wr       = (const float*)d_in[12];
    const float* br       = (const float*)d_in[13];

    const int N = in_sizes[0];        // IN == 1
    const int E = in_sizes[1] / 2;
    const int G = out_size / 65;      // pred[G] + pooled[G*64]

    // workspace carve-up (256B aligned)
    char* ws = (char*)d_ws;
    size_t off = 0;
    auto take = [&](size_t bytes) {
        void* p = ws + off;
        off = (off + bytes + 255) & ~(size_t)255;
        return p;
    };
    int*   counts    = (int*)take(sizeof(int) * N);
    int*   cursor    = (int*)take(sizeof(int) * N);
    int*   row_start = (int*)take(sizeof(int) * (N + 1));
    int*   csr_src   = (int*)take(sizeof(int) * (E + N));
    float* as        = (float*)take(sizeof(float) * N);
    float* ad        = (float*)take(sizeof(float) * N);
    float* h         = (float*)take(sizeof(float) * (size_t)N * 64);
    float* xa        = (float*)take(sizeof(float) * (size_t)N * 64);
    float* xb        = (float*)take(sizeof(float) * (size_t)N * 64);
    int*   gcnt      = (int*)take(sizeof(int) * G);
    int*   gstart    = (int*)take(sizeof(int) * G);
    (void)ws_size;

    const int* esrc = ei;
    const int* edst = ei + E;

    hipMemsetAsync(gcnt, 0, sizeof(int) * G, stream);

    int nbN = (N + 255) / 256;
    init_counts_kernel<<<nbN, 256, 0, stream>>>(counts, N);
    count_kernel<<<(E + 255) / 256, 256, 0, stream>>>(edst, counts, E);
    scan_kernel<<<1, 1024, 0, stream>>>(counts, row_start, cursor, N);
    scatter_kernel<<<(E + N + 255) / 256, 256, 0, stream>>>(esrc, edst, cursor, csr_src, E, N);

    int wb = (N + 3) / 4;  // 4 waves (nodes) per 256-thread block
    layer1_kernel<<<wb, 256, 0, stream>>>(X, W1, att_src, att_dst, h, as, ad, N);
    aggregate_kernel<<<wb, 256, 0, stream>>>(h, as, ad, row_start, csr_src,
                                             bias, bn_gamma, bn_beta, bn_mean, bn_var, xa, N);
    float* xin = xa;
    float* xout = xb;
    for (int L = 1; L < 5; ++L) {
        transform_kernel<<<wb, 256, 0, stream>>>(xin, Ws + (size_t)(L - 1) * 64 * 64,
                                                 att_src + (size_t)L * 64, att_dst + (size_t)L * 64,
                                                 h, as, ad, N);
        aggregate_kernel<<<wb, 256, 0, stream>>>(h, as, ad, row_start, csr_src,
                                                 bias + (size_t)L * 64, bn_gamma + (size_t)L * 64,
                                                 bn_beta + (size_t)L * 64, bn_mean + (size_t)L * 64,
                                                 bn_var + (size_t)L * 64, xout, N);
        float* t = xin; xin = xout; xout = t;
    }

    gcount_kernel<<<nbN, 256, 0, stream>>>(batch, gcnt, N);
    gscan_kernel<<<1, 256, 0, stream>>>(gcnt, gstart, G);
    pool_kernel<<<(G + 3) / 4, 256, 0, stream>>>(xin, gstart, gcnt, Wr, br, (float*)d_out, G);
}

// Round 2
// 757.612 us; speedup vs baseline: 1.4263x; 1.4263x over previous
//
#include <hip/hip_runtime.h>
#include <math.h>

// ---------------------------------------------------------------------------
// GAT regression: 5x (GATConv -> ReLU -> BN) -> mean pool -> linear head.
// fp32 end-to-end. CSR-by-dst built on device each launch (deterministic work).
// R1: hierarchical scan (was 111us single-block), 4x-unrolled aggregate gather.
// ---------------------------------------------------------------------------

__global__ __launch_bounds__(256) void init_counts_kernel(int* __restrict__ counts, int N) {
    int i = blockIdx.x * blockDim.x + threadIdx.x;
    if (i < N) counts[i] = 1;  // self-loop contributes 1 in-edge per node
}

__global__ __launch_bounds__(256) void count_kernel(const int* __restrict__ edst,
                                                    int* __restrict__ counts, int E) {
    int i = blockIdx.x * blockDim.x + threadIdx.x;
    if (i < E) atomicAdd(&counts[edst[i]], 1);
}

// --- hierarchical exclusive scan: 196 blocks of 256 ---------------------------
__global__ __launch_bounds__(256) void block_sum_kernel(const int* __restrict__ counts,
                                                        int* __restrict__ bsum, int N) {
    int i = blockIdx.x * 256 + threadIdx.x;
    int v = (i < N) ? counts[i] : 0;
#pragma unroll
    for (int o = 32; o > 0; o >>= 1) v += __shfl_xor(v, o, 64);
    __shared__ int wsum[4];
    if ((threadIdx.x & 63) == 0) wsum[threadIdx.x >> 6] = v;
    __syncthreads();
    if (threadIdx.x == 0) bsum[blockIdx.x] = wsum[0] + wsum[1] + wsum[2] + wsum[3];
}

// single block scans nb (<=256) block sums -> exclusive block offsets
__global__ __launch_bounds__(256) void scan_bsum_kernel(const int* __restrict__ bsum,
                                                        int* __restrict__ boff, int nb) {
    __shared__ int buf[256];
    int t = threadIdx.x;
    int v = (t < nb) ? bsum[t] : 0;
    buf[t] = v;
    __syncthreads();
    for (int o = 1; o < 256; o <<= 1) {
        int u = (t >= o) ? buf[t - o] : 0;
        __syncthreads();
        buf[t] += u;
        __syncthreads();
    }
    if (t < nb) boff[t] = buf[t] - v;
}

__global__ __launch_bounds__(256) void scan_final_kernel(const int* __restrict__ counts,
                                                         const int* __restrict__ boff,
                                                         int* __restrict__ row_start,
                                                         int* __restrict__ cursor, int N, int T) {
    __shared__ int buf[256];
    int t = threadIdx.x;
    int i = blockIdx.x * 256 + t;
    int v = (i < N) ? counts[i] : 0;
    buf[t] = v;
    __syncthreads();
    for (int o = 1; o < 256; o <<= 1) {
        int u = (t >= o) ? buf[t - o] : 0;
        __syncthreads();
        buf[t] += u;
        __syncthreads();
    }
    int excl = buf[t] - v + boff[blockIdx.x];
    if (i < N) { row_start[i] = excl; cursor[i] = excl; }
    if (i == N - 1) row_start[N] = T;
}
// -----------------------------------------------------------------------------

__global__ __launch_bounds__(256) void scatter_kernel(const int* __restrict__ esrc,
                                                      const int* __restrict__ edst,
                                                      int* __restrict__ cursor,
                                                      int* __restrict__ csr_src,
                                                      int E, int N) {
    int i = blockIdx.x * blockDim.x + threadIdx.x;
    int T = E + N;
    if (i >= T) return;
    int s, d;
    if (i < E) { s = esrc[i]; d = edst[i]; }
    else       { s = i - E;   d = s; }       // self loops appended after edges
    int pos = atomicAdd(&cursor[d], 1);
    csr_src[pos] = s;
}

// Layer 1: x is [N,1], W1 is [1,64] -> h[n][c] = X[n]*W1[c]; alpha dots collapse.
__global__ __launch_bounds__(256) void layer1_kernel(const float* __restrict__ X,
                                                     const float* __restrict__ W1,
                                                     const float* __restrict__ a_s,
                                                     const float* __restrict__ a_d,
                                                     float* __restrict__ h,
                                                     float* __restrict__ as,
                                                     float* __restrict__ ad, int N) {
    int lane = threadIdx.x & 63;
    int wave = threadIdx.x >> 6;
    int wpb  = blockDim.x >> 6;
    float w  = W1[lane];
    float da = w * a_s[lane];
    float db = w * a_d[lane];
#pragma unroll
    for (int o = 32; o > 0; o >>= 1) {
        da += __shfl_xor(da, o, 64);
        db += __shfl_xor(db, o, 64);
    }
    for (int n = blockIdx.x * wpb + wave; n < N; n += gridDim.x * wpb) {
        float xv = X[n];
        h[(size_t)n * 64 + lane] = xv * w;
        if (lane == 0) { as[n] = xv * da; ad[n] = xv * db; }
    }
}

// Layers 2..5 transform: h = x @ W ([64,64] in LDS), plus per-node alpha dots.
__global__ __launch_bounds__(256) void transform_kernel(const float* __restrict__ x,
                                                        const float* __restrict__ W,
                                                        const float* __restrict__ a_s,
                                                        const float* __restrict__ a_d,
                                                        float* __restrict__ h,
                                                        float* __restrict__ as,
                                                        float* __restrict__ ad, int N) {
    __shared__ float Wl[64 * 64];
    for (int i = threadIdx.x; i < 64 * 64; i += blockDim.x) Wl[i] = W[i];
    __syncthreads();
    int lane = threadIdx.x & 63;
    int wave = threadIdx.x >> 6;
    int wpb  = blockDim.x >> 6;
    float asc = a_s[lane], adc = a_d[lane];
    for (int n = blockIdx.x * wpb + wave; n < N; n += gridDim.x * wpb) {
        float xv  = x[(size_t)n * 64 + lane];
        float acc = 0.f;
#pragma unroll
        for (int k = 0; k < 64; ++k) {
            float xk = __shfl(xv, k, 64);
            acc = fmaf(xk, Wl[k * 64 + lane], acc);
        }
        h[(size_t)n * 64 + lane] = acc;
        float s1 = acc * asc, s2 = acc * adc;
#pragma unroll
        for (int o = 32; o > 0; o >>= 1) {
            s1 += __shfl_xor(s1, o, 64);
            s2 += __shfl_xor(s2, o, 64);
        }
        if (lane == 0) { as[n] = s1; ad[n] = s2; }
    }
}

// Per-dst-node softmax + weighted sum over in-edges; fused bias+ReLU+BN epilogue.
// One wave per node, lane = channel. Pass 2 unrolled x4 for gather ILP.
__global__ __launch_bounds__(256) void aggregate_kernel(const float* __restrict__ h,
                                                        const float* __restrict__ as,
                                                        const float* __restrict__ ad,
                                                        const int* __restrict__ row_start,
                                                        const int* __restrict__ csr_src,
                                                        const float* __restrict__ bias,
                                                        const float* __restrict__ gamma,
                                                        const float* __restrict__ beta,
                                                        const float* __restrict__ mean,
                                                        const float* __restrict__ var,
                                                        float* __restrict__ xout, int N) {
    int lane = threadIdx.x & 63;
    int wave = threadIdx.x >> 6;
    int wpb  = blockDim.x >> 6;
    float bc    = bias[lane];
    float scale = gamma[lane] * rsqrtf(var[lane] + 1e-5f);
    float shift = beta[lane] - mean[lane] * scale;
    for (int d = blockIdx.x * wpb + wave; d < N; d += gridDim.x * wpb) {
        int rs = row_start[d], re = row_start[d + 1];
        float add = ad[d];
        // pass 1: segment max (lanes parallel over edges)
        float m = -INFINITY;
        for (int j = rs + lane; j < re; j += 64) {
            int s   = csr_src[j];
            float e = as[s] + add;
            e = (e > 0.f) ? e : 0.2f * e;
            m = fmaxf(m, e);
        }
#pragma unroll
        for (int o = 32; o > 0; o >>= 1) m = fmaxf(m, __shfl_xor(m, o, 64));
        // pass 2: exp-sum + weighted gather of h[src], 4-wide for load ILP
        float z = 0.f, acc = 0.f;
        int j = rs;
        for (; j + 4 <= re; j += 4) {
            int s0 = csr_src[j + 0], s1 = csr_src[j + 1];
            int s2 = csr_src[j + 2], s3 = csr_src[j + 3];
            float a0 = as[s0], a1 = as[s1], a2 = as[s2], a3 = as[s3];
            float h0 = h[(size_t)s0 * 64 + lane], h1 = h[(size_t)s1 * 64 + lane];
            float h2 = h[(size_t)s2 * 64 + lane], h3 = h[(size_t)s3 * 64 + lane];
            float e0 = a0 + add; e0 = (e0 > 0.f) ? e0 : 0.2f * e0;
            float e1 = a1 + add; e1 = (e1 > 0.f) ? e1 : 0.2f * e1;
            float e2 = a2 + add; e2 = (e2 > 0.f) ? e2 : 0.2f * e2;
            float e3 = a3 + add; e3 = (e3 > 0.f) ? e3 : 0.2f * e3;
            float w0 = __expf(e0 - m), w1 = __expf(e1 - m);
            float w2 = __expf(e2 - m), w3 = __expf(e3 - m);
            z += (w0 + w1) + (w2 + w3);
            acc = fmaf(h0, w0, acc);
            acc = fmaf(h1, w1, acc);
            acc = fmaf(h2, w2, acc);
            acc = fmaf(h3, w3, acc);
        }
        for (; j < re; ++j) {
            int s   = csr_src[j];
            float e = as[s] + add;
            e = (e > 0.f) ? e : 0.2f * e;
            float w = __expf(e - m);
            z += w;
            acc = fmaf(h[(size_t)s * 64 + lane], w, acc);
        }
        float o = acc / z + bc;
        o = fmaxf(o, 0.f);                       // ReLU
        xout[(size_t)d * 64 + lane] = fmaf(o, scale, shift);  // BN (eval)
    }
}

__global__ __launch_bounds__(256) void gcount_kernel(const int* __restrict__ batch,
                                                     int* __restrict__ gcnt, int N) {
    int i = blockIdx.x * blockDim.x + threadIdx.x;
    if (i < N) atomicAdd(&gcnt[batch[i]], 1);
}

__global__ __launch_bounds__(256) void gscan_kernel(const int* __restrict__ gcnt,
                                                    int* __restrict__ gstart, int G) {
    __shared__ int buf[256];
    int t = threadIdx.x;
    buf[t] = (t < G) ? gcnt[t] : 0;
    __syncthreads();
    for (int off = 1; off < 256; off <<= 1) {
        int v = (t >= off) ? buf[t - off] : 0;
        __syncthreads();
        buf[t] += v;
        __syncthreads();
    }
    if (t < G) gstart[t] = buf[t] - gcnt[t];  // exclusive
}

// One wave per graph: mean pool (batch is sorted -> contiguous) + linear head.
__global__ __launch_bounds__(256) void pool_kernel(const float* __restrict__ x,
                                                   const int* __restrict__ gstart,
                                                   const int* __restrict__ gcnt,
                                                   const float* __restrict__ Wr,
                                                   const float* __restrict__ br,
                                                   float* __restrict__ out, int G) {
    int lane = threadIdx.x & 63;
    int wave = threadIdx.x >> 6;
    int wpb  = blockDim.x >> 6;
    for (int g = blockIdx.x * wpb + wave; g < G; g += gridDim.x * wpb) {
        int s = gstart[g], cnt = gcnt[g];
        float acc = 0.f;
        for (int n = s; n < s + cnt; ++n) acc += x[(size_t)n * 64 + lane];
        float pooled = acc / fmaxf((float)cnt, 1.f);
        out[G + (size_t)g * 64 + lane] = pooled;  // pooled section after pred[G]
        float p = pooled * Wr[lane];
#pragma unroll
        for (int o = 32; o > 0; o >>= 1) p += __shfl_xor(p, o, 64);
        if (lane == 0) out[g] = p + br[0];
    }
}

extern "C" void kernel_launch(void* const* d_in, const int* in_sizes, int n_in,
                              void* d_out, int out_size, void* d_ws, size_t ws_size,
                              hipStream_t stream) {
    const float* X        = (const float*)d_in[0];
    const int*   ei       = (const int*)d_in[1];
    const int*   batch    = (const int*)d_in[2];
    const float* W1       = (const float*)d_in[3];
    const float* Ws       = (const float*)d_in[4];
    const float* att_src  = (const float*)d_in[5];
    const float* att_dst  = (const float*)d_in[6];
    const float* bias     = (const float*)d_in[7];
    const float* bn_gamma = (const float*)d_in[8];
    const float* bn_beta  = (const float*)d_in[9];
    const float* bn_mean  = (const float*)d_in[10];
    const float* bn_var   = (const float*)d_in[11];
    const float* Wr       = (const float*)d_in[12];
    const float* br       = (const float*)d_in[13];

    const int N = in_sizes[0];        // IN == 1
    const int E = in_sizes[1] / 2;
    const int G = out_size / 65;      // pred[G] + pooled[G*64]

    // workspace carve-up (256B aligned)
    char* ws = (char*)d_ws;
    size_t off = 0;
    auto take = [&](size_t bytes) {
        void* p = ws + off;
        off = (off + bytes + 255) & ~(size_t)255;
        return p;
    };
    int nb = (N + 255) / 256;         // scan blocks (196 for N=50000, must be <=256)
    int*   counts    = (int*)take(sizeof(int) * N);
    int*   cursor    = (int*)take(sizeof(int) * N);
    int*   row_start = (int*)take(sizeof(int) * (N + 1));
    int*   csr_src   = (int*)take(sizeof(int) * (E + N));
    float* as        = (float*)take(sizeof(float) * N);
    float* ad        = (float*)take(sizeof(float) * N);
    float* h         = (float*)take(sizeof(float) * (size_t)N * 64);
    float* xa        = (float*)take(sizeof(float) * (size_t)N * 64);
    float* xb        = (float*)take(sizeof(float) * (size_t)N * 64);
    int*   gcnt      = (int*)take(sizeof(int) * G);
    int*   gstart    = (int*)take(sizeof(int) * G);
    int*   bsum      = (int*)take(sizeof(int) * nb);
    int*   boff      = (int*)take(sizeof(int) * nb);
    (void)ws_size;

    const int* esrc = ei;
    const int* edst = ei + E;

    hipMemsetAsync(gcnt, 0, sizeof(int) * G, stream);

    int nbN = (N + 255) / 256;
    init_counts_kernel<<<nbN, 256, 0, stream>>>(counts, N);
    count_kernel<<<(E + 255) / 256, 256, 0, stream>>>(edst, counts, E);
    block_sum_kernel<<<nb, 256, 0, stream>>>(counts, bsum, N);
    scan_bsum_kernel<<<1, 256, 0, stream>>>(bsum, boff, nb);
    scan_final_kernel<<<nb, 256, 0, stream>>>(counts, boff, row_start, cursor, N, E + N);
    scatter_kernel<<<(E + N + 255) / 256, 256, 0, stream>>>(esrc, edst, cursor, csr_src, E, N);

    int wb = (N + 3) / 4;  // 4 waves (nodes) per 256-thread block
    layer1_kernel<<<wb, 256, 0, stream>>>(X, W1, att_src, att_dst, h, as, ad, N);
    aggregate_kernel<<<wb, 256, 0, stream>>>(h, as, ad, row_start, csr_src,
                                             bias, bn_gamma, bn_beta, bn_mean, bn_var, xa, N);
    float* xin = xa;
    float* xout = xb;
    for (int L = 1; L < 5; ++L) {
        transform_kernel<<<wb, 256, 0, stream>>>(xin, Ws + (size_t)(L - 1) * 64 * 64,
                                                 att_src + (size_t)L * 64, att_dst + (size_t)L * 64,
                                                 h, as, ad, N);
        aggregate_kernel<<<wb, 256, 0, stream>>>(h, as, ad, row_start, csr_src,
                                                 bias + (size_t)L * 64, bn_gamma + (size_t)L * 64,
                                                 bn_beta + (size_t)L * 64, bn_mean + (size_t)L * 64,
                                                 bn_var + (size_t)L * 64, xout, N);
        float* t = xin; xin = xout; xout = t;
    }

    gcount_kernel<<<nbN, 256, 0, stream>>>(batch, gcnt, N);
    gscan_kernel<<<1, 256, 0, stream>>>(gcnt, gstart, G);
    pool_kernel<<<(G + 3) / 4, 256, 0, stream>>>(xin, gstart, gcnt, Wr, br, (float*)d_out, G);
}

// Round 3
// 562.321 us; speedup vs baseline: 1.9216x; 1.3473x over previous
//
#include <hip/hip_runtime.h>
#include <math.h>

// ---------------------------------------------------------------------------
// GAT regression: 5x (GATConv -> ReLU -> BN) -> mean pool -> linear head.
// fp32 end-to-end. CSR-by-dst built on device each launch (deterministic work).
// R1: hierarchical scan. R2: transform = register-tiled GEMM (was shuffle-bound).
// ---------------------------------------------------------------------------

__global__ __launch_bounds__(256) void init_counts_kernel(int* __restrict__ counts, int N) {
    int i = blockIdx.x * blockDim.x + threadIdx.x;
    if (i < N) counts[i] = 1;  // self-loop contributes 1 in-edge per node
}

__global__ __launch_bounds__(256) void count_kernel(const int* __restrict__ edst,
                                                    int* __restrict__ counts, int E) {
    int i = blockIdx.x * blockDim.x + threadIdx.x;
    if (i < E) atomicAdd(&counts[edst[i]], 1);
}

// --- hierarchical exclusive scan ----------------------------------------------
__global__ __launch_bounds__(256) void block_sum_kernel(const int* __restrict__ counts,
                                                        int* __restrict__ bsum, int N) {
    int i = blockIdx.x * 256 + threadIdx.x;
    int v = (i < N) ? counts[i] : 0;
#pragma unroll
    for (int o = 32; o > 0; o >>= 1) v += __shfl_xor(v, o, 64);
    __shared__ int wsum[4];
    if ((threadIdx.x & 63) == 0) wsum[threadIdx.x >> 6] = v;
    __syncthreads();
    if (threadIdx.x == 0) bsum[blockIdx.x] = wsum[0] + wsum[1] + wsum[2] + wsum[3];
}

__global__ __launch_bounds__(256) void scan_bsum_kernel(const int* __restrict__ bsum,
                                                        int* __restrict__ boff, int nb) {
    __shared__ int buf[256];
    int t = threadIdx.x;
    int v = (t < nb) ? bsum[t] : 0;
    buf[t] = v;
    __syncthreads();
    for (int o = 1; o < 256; o <<= 1) {
        int u = (t >= o) ? buf[t - o] : 0;
        __syncthreads();
        buf[t] += u;
        __syncthreads();
    }
    if (t < nb) boff[t] = buf[t] - v;
}

__global__ __launch_bounds__(256) void scan_final_kernel(const int* __restrict__ counts,
                                                         const int* __restrict__ boff,
                                                         int* __restrict__ row_start,
                                                         int* __restrict__ cursor, int N, int T) {
    __shared__ int buf[256];
    int t = threadIdx.x;
    int i = blockIdx.x * 256 + t;
    int v = (i < N) ? counts[i] : 0;
    buf[t] = v;
    __syncthreads();
    for (int o = 1; o < 256; o <<= 1) {
        int u = (t >= o) ? buf[t - o] : 0;
        __syncthreads();
        buf[t] += u;
        __syncthreads();
    }
    int excl = buf[t] - v + boff[blockIdx.x];
    if (i < N) { row_start[i] = excl; cursor[i] = excl; }
    if (i == N - 1) row_start[N] = T;
}
// -----------------------------------------------------------------------------

__global__ __launch_bounds__(256) void scatter_kernel(const int* __restrict__ esrc,
                                                      const int* __restrict__ edst,
                                                      int* __restrict__ cursor,
                                                      int* __restrict__ csr_src,
                                                      int E, int N) {
    int i = blockIdx.x * blockDim.x + threadIdx.x;
    int T = E + N;
    if (i >= T) return;
    int s, d;
    if (i < E) { s = esrc[i]; d = edst[i]; }
    else       { s = i - E;   d = s; }       // self loops appended after edges
    int pos = atomicAdd(&cursor[d], 1);
    csr_src[pos] = s;
}

// Layer 1: x is [N,1], W1 is [1,64] -> h[n][c] = X[n]*W1[c]; alpha dots collapse.
__global__ __launch_bounds__(256) void layer1_kernel(const float* __restrict__ X,
                                                     const float* __restrict__ W1,
                                                     const float* __restrict__ a_s,
                                                     const float* __restrict__ a_d,
                                                     float* __restrict__ h,
                                                     float* __restrict__ as,
                                                     float* __restrict__ ad, int N) {
    int lane = threadIdx.x & 63;
    int wave = threadIdx.x >> 6;
    int wpb  = blockDim.x >> 6;
    float w  = W1[lane];
    float da = w * a_s[lane];
    float db = w * a_d[lane];
#pragma unroll
    for (int o = 32; o > 0; o >>= 1) {
        da += __shfl_xor(da, o, 64);
        db += __shfl_xor(db, o, 64);
    }
    for (int n = blockIdx.x * wpb + wave; n < N; n += gridDim.x * wpb) {
        float xv = X[n];
        h[(size_t)n * 64 + lane] = xv * w;
        if (lane == 0) { as[n] = xv * da; ad[n] = xv * db; }
    }
}

// Layers 2..5 transform: register-tiled GEMM. 64-node tile/block, 256 threads,
// each thread computes 4 nodes x 4 channels. x tile staged TRANSPOSED in LDS
// (stride 68: float4-aligned, conflict-free reads). Alpha dots fused via
// 16-lane shuffle reduction over the register tile.
__global__ __launch_bounds__(256) void transform_kernel(const float* __restrict__ x,
                                                        const float* __restrict__ W,
                                                        const float* __restrict__ a_s,
                                                        const float* __restrict__ a_d,
                                                        float* __restrict__ h,
                                                        float* __restrict__ as,
                                                        float* __restrict__ ad, int N) {
    __shared__ float Wl[64 * 64];
    __shared__ float xT[64 * 68];   // [k][n], stride 68 (mult of 4 -> b128-aligned)
    int t    = threadIdx.x;
    int lane = t & 63;
    int wv   = t >> 6;
    int base = blockIdx.x * 64;

    for (int i = t; i < 64 * 64; i += 256) Wl[i] = W[i];
#pragma unroll
    for (int r = 0; r < 16; ++r) {          // wave wv stages nodes wv*16..wv*16+15
        int nl = wv * 16 + r;
        int n  = base + nl;
        float v = (n < N) ? x[(size_t)n * 64 + lane] : 0.f;
        xT[lane * 68 + nl] = v;             // transpose: k=lane
    }
    __syncthreads();

    int c0  = (t & 15) * 4;                 // 4 output channels
    int nl0 = (t >> 4) * 4;                 // 4 nodes
    float acc[4][4] = {{0.f}};
#pragma unroll 8
    for (int k = 0; k < 64; ++k) {
        float4 xv = *reinterpret_cast<const float4*>(&xT[k * 68 + nl0]);
        float4 wl = *reinterpret_cast<const float4*>(&Wl[k * 64 + c0]);
        acc[0][0] = fmaf(xv.x, wl.x, acc[0][0]);
        acc[0][1] = fmaf(xv.x, wl.y, acc[0][1]);
        acc[0][2] = fmaf(xv.x, wl.z, acc[0][2]);
        acc[0][3] = fmaf(xv.x, wl.w, acc[0][3]);
        acc[1][0] = fmaf(xv.y, wl.x, acc[1][0]);
        acc[1][1] = fmaf(xv.y, wl.y, acc[1][1]);
        acc[1][2] = fmaf(xv.y, wl.z, acc[1][2]);
        acc[1][3] = fmaf(xv.y, wl.w, acc[1][3]);
        acc[2][0] = fmaf(xv.z, wl.x, acc[2][0]);
        acc[2][1] = fmaf(xv.z, wl.y, acc[2][1]);
        acc[2][2] = fmaf(xv.z, wl.z, acc[2][2]);
        acc[2][3] = fmaf(xv.z, wl.w, acc[2][3]);
        acc[3][0] = fmaf(xv.w, wl.x, acc[3][0]);
        acc[3][1] = fmaf(xv.w, wl.y, acc[3][1]);
        acc[3][2] = fmaf(xv.w, wl.z, acc[3][2]);
        acc[3][3] = fmaf(xv.w, wl.w, acc[3][3]);
    }

    float4 asv = *reinterpret_cast<const float4*>(&a_s[c0]);
    float4 adv = *reinterpret_cast<const float4*>(&a_d[c0]);
#pragma unroll
    for (int i = 0; i < 4; ++i) {
        int n = base + nl0 + i;
        // store h row chunk
        if (n < N) {
            float4 o = make_float4(acc[i][0], acc[i][1], acc[i][2], acc[i][3]);
            *reinterpret_cast<float4*>(&h[(size_t)n * 64 + c0]) = o;
        }
        // fused alpha dots: reduce over the 16 threads covering this node's channels
        float s1 = acc[i][0] * asv.x + acc[i][1] * asv.y + acc[i][2] * asv.z + acc[i][3] * asv.w;
        float s2 = acc[i][0] * adv.x + acc[i][1] * adv.y + acc[i][2] * adv.z + acc[i][3] * adv.w;
#pragma unroll
        for (int o = 8; o > 0; o >>= 1) {   // lanes sharing (t>>4) are 16 consecutive
            s1 += __shfl_xor(s1, o, 64);
            s2 += __shfl_xor(s2, o, 64);
        }
        if ((lane & 15) == 0 && n < N) { as[n] = s1; ad[n] = s2; }
    }
}

// Per-dst-node softmax + weighted sum over in-edges; fused bias+ReLU+BN epilogue.
// One wave per node, lane = channel. Pass 2 unrolled x4 for gather ILP.
__global__ __launch_bounds__(256) void aggregate_kernel(const float* __restrict__ h,
                                                        const float* __restrict__ as,
                                                        const float* __restrict__ ad,
                                                        const int* __restrict__ row_start,
                                                        const int* __restrict__ csr_src,
                                                        const float* __restrict__ bias,
                                                        const float* __restrict__ gamma,
                                                        const float* __restrict__ beta,
                                                        const float* __restrict__ mean,
                                                        const float* __restrict__ var,
                                                        float* __restrict__ xout, int N) {
    int lane = threadIdx.x & 63;
    int wave = threadIdx.x >> 6;
    int wpb  = blockDim.x >> 6;
    float bc    = bias[lane];
    float scale = gamma[lane] * rsqrtf(var[lane] + 1e-5f);
    float shift = beta[lane] - mean[lane] * scale;
    for (int d = blockIdx.x * wpb + wave; d < N; d += gridDim.x * wpb) {
        int rs = row_start[d], re = row_start[d + 1];
        float add = ad[d];
        // pass 1: segment max (lanes parallel over edges)
        float m = -INFINITY;
        for (int j = rs + lane; j < re; j += 64) {
            int s   = csr_src[j];
            float e = as[s] + add;
            e = (e > 0.f) ? e : 0.2f * e;
            m = fmaxf(m, e);
        }
#pragma unroll
        for (int o = 32; o > 0; o >>= 1) m = fmaxf(m, __shfl_xor(m, o, 64));
        // pass 2: exp-sum + weighted gather of h[src], 4-wide for load ILP
        float z = 0.f, acc = 0.f;
        int j = rs;
        for (; j + 4 <= re; j += 4) {
            int s0 = csr_src[j + 0], s1 = csr_src[j + 1];
            int s2 = csr_src[j + 2], s3 = csr_src[j + 3];
            float a0 = as[s0], a1 = as[s1], a2 = as[s2], a3 = as[s3];
            float h0 = h[(size_t)s0 * 64 + lane], h1 = h[(size_t)s1 * 64 + lane];
            float h2 = h[(size_t)s2 * 64 + lane], h3 = h[(size_t)s3 * 64 + lane];
            float e0 = a0 + add; e0 = (e0 > 0.f) ? e0 : 0.2f * e0;
            float e1 = a1 + add; e1 = (e1 > 0.f) ? e1 : 0.2f * e1;
            float e2 = a2 + add; e2 = (e2 > 0.f) ? e2 : 0.2f * e2;
            float e3 = a3 + add; e3 = (e3 > 0.f) ? e3 : 0.2f * e3;
            float w0 = __expf(e0 - m), w1 = __expf(e1 - m);
            float w2 = __expf(e2 - m), w3 = __expf(e3 - m);
            z += (w0 + w1) + (w2 + w3);
            acc = fmaf(h0, w0, acc);
            acc = fmaf(h1, w1, acc);
            acc = fmaf(h2, w2, acc);
            acc = fmaf(h3, w3, acc);
        }
        for (; j < re; ++j) {
            int s   = csr_src[j];
            float e = as[s] + add;
            e = (e > 0.f) ? e : 0.2f * e;
            float w = __expf(e - m);
            z += w;
            acc = fmaf(h[(size_t)s * 64 + lane], w, acc);
        }
        float o = acc / z + bc;
        o = fmaxf(o, 0.f);                       // ReLU
        xout[(size_t)d * 64 + lane] = fmaf(o, scale, shift);  // BN (eval)
    }
}

__global__ __launch_bounds__(256) void gcount_kernel(const int* __restrict__ batch,
                                                     int* __restrict__ gcnt, int N) {
    int i = blockIdx.x * blockDim.x + threadIdx.x;
    if (i < N) atomicAdd(&gcnt[batch[i]], 1);
}

__global__ __launch_bounds__(256) void gscan_kernel(const int* __restrict__ gcnt,
                                                    int* __restrict__ gstart, int G) {
    __shared__ int buf[256];
    int t = threadIdx.x;
    buf[t] = (t < G) ? gcnt[t] : 0;
    __syncthreads();
    for (int off = 1; off < 256; off <<= 1) {
        int v = (t >= off) ? buf[t - off] : 0;
        __syncthreads();
        buf[t] += v;
        __syncthreads();
    }
    if (t < G) gstart[t] = buf[t] - gcnt[t];  // exclusive
}

// One wave per graph: mean pool (batch is sorted -> contiguous) + linear head.
__global__ __launch_bounds__(256) void pool_kernel(const float* __restrict__ x,
                                                   const int* __restrict__ gstart,
                                                   const int* __restrict__ gcnt,
                                                   const float* __restrict__ Wr,
                                                   const float* __restrict__ br,
                                                   float* __restrict__ out, int G) {
    int lane = threadIdx.x & 63;
    int wave = threadIdx.x >> 6;
    int wpb  = blockDim.x >> 6;
    for (int g = blockIdx.x * wpb + wave; g < G; g += gridDim.x * wpb) {
        int s = gstart[g], cnt = gcnt[g];
        float acc = 0.f;
        for (int n = s; n < s + cnt; ++n) acc += x[(size_t)n * 64 + lane];
        float pooled = acc / fmaxf((float)cnt, 1.f);
        out[G + (size_t)g * 64 + lane] = pooled;  // pooled section after pred[G]
        float p = pooled * Wr[lane];
#pragma unroll
        for (int o = 32; o > 0; o >>= 1) p += __shfl_xor(p, o, 64);
        if (lane == 0) out[g] = p + br[0];
    }
}

extern "C" void kernel_launch(void* const* d_in, const int* in_sizes, int n_in,
                              void* d_out, int out_size, void* d_ws, size_t ws_size,
                              hipStream_t stream) {
    const float* X        = (const float*)d_in[0];
    const int*   ei       = (const int*)d_in[1];
    const int*   batch    = (const int*)d_in[2];
    const float* W1       = (const float*)d_in[3];
    const float* Ws       = (const float*)d_in[4];
    const float* att_src  = (const float*)d_in[5];
    const float* att_dst  = (const float*)d_in[6];
    const float* bias     = (const float*)d_in[7];
    const float* bn_gamma = (const float*)d_in[8];
    const float* bn_beta  = (const float*)d_in[9];
    const float* bn_mean  = (const float*)d_in[10];
    const float* bn_var   = (const float*)d_in[11];
    const float* Wr       = (const float*)d_in[12];
    const float* br       = (const float*)d_in[13];

    const int N = in_sizes[0];        // IN == 1
    const int E = in_sizes[1] / 2;
    const int G = out_size / 65;      // pred[G] + pooled[G*64]

    // workspace carve-up (256B aligned)
    char* ws = (char*)d_ws;
    size_t off = 0;
    auto take = [&](size_t bytes) {
        void* p = ws + off;
        off = (off + bytes + 255) & ~(size_t)255;
        return p;
    };
    int nb = (N + 255) / 256;         // scan blocks (196 for N=50000, must be <=256)
    int*   counts    = (int*)take(sizeof(int) * N);
    int*   cursor    = (int*)take(sizeof(int) * N);
    int*   row_start = (int*)take(sizeof(int) * (N + 1));
    int*   csr_src   = (int*)take(sizeof(int) * (E + N));
    float* as        = (float*)take(sizeof(float) * N);
    float* ad        = (float*)take(sizeof(float) * N);
    float* h         = (float*)take(sizeof(float) * (size_t)N * 64);
    float* xa        = (float*)take(sizeof(float) * (size_t)N * 64);
    float* xb        = (float*)take(sizeof(float) * (size_t)N * 64);
    int*   gcnt      = (int*)take(sizeof(int) * G);
    int*   gstart    = (int*)take(sizeof(int) * G);
    int*   bsum      = (int*)take(sizeof(int) * nb);
    int*   boff      = (int*)take(sizeof(int) * nb);
    (void)ws_size;

    const int* esrc = ei;
    const int* edst = ei + E;

    hipMemsetAsync(gcnt, 0, sizeof(int) * G, stream);

    int nbN = (N + 255) / 256;
    init_counts_kernel<<<nbN, 256, 0, stream>>>(counts, N);
    count_kernel<<<(E + 255) / 256, 256, 0, stream>>>(edst, counts, E);
    block_sum_kernel<<<nb, 256, 0, stream>>>(counts, bsum, N);
    scan_bsum_kernel<<<1, 256, 0, stream>>>(bsum, boff, nb);
    scan_final_kernel<<<nb, 256, 0, stream>>>(counts, boff, row_start, cursor, N, E + N);
    scatter_kernel<<<(E + N + 255) / 256, 256, 0, stream>>>(esrc, edst, cursor, csr_src, E, N);

    int wb  = (N + 3) / 4;   // aggregate: 4 waves (nodes) per 256-thread block
    int tb  = (N + 63) / 64; // transform: 64-node tiles
    layer1_kernel<<<wb, 256, 0, stream>>>(X, W1, att_src, att_dst, h, as, ad, N);
    aggregate_kernel<<<wb, 256, 0, stream>>>(h, as, ad, row_start, csr_src,
                                             bias, bn_gamma, bn_beta, bn_mean, bn_var, xa, N);
    float* xin = xa;
    float* xout = xb;
    for (int L = 1; L < 5; ++L) {
        transform_kernel<<<tb, 256, 0, stream>>>(xin, Ws + (size_t)(L - 1) * 64 * 64,
                                                 att_src + (size_t)L * 64, att_dst + (size_t)L * 64,
                                                 h, as, ad, N);
        aggregate_kernel<<<wb, 256, 0, stream>>>(h, as, ad, row_start, csr_src,
                                                 bias + (size_t)L * 64, bn_gamma + (size_t)L * 64,
                                                 bn_beta + (size_t)L * 64, bn_mean + (size_t)L * 64,
                                                 bn_var + (size_t)L * 64, xout, N);
        float* t = xin; xin = xout; xout = t;
    }

    gcount_kernel<<<nbN, 256, 0, stream>>>(batch, gcnt, N);
    gscan_kernel<<<1, 256, 0, stream>>>(gcnt, gstart, G);
    pool_kernel<<<(G + 3) / 4, 256, 0, stream>>>(xin, gstart, gcnt, Wr, br, (float*)d_out, G);
}

// Round 4
// 511.443 us; speedup vs baseline: 2.1127x; 1.0995x over previous
//
#include <hip/hip_runtime.h>
#include <math.h>

// ---------------------------------------------------------------------------
// GAT regression: 5x (GATConv -> ReLU -> BN) -> mean pool -> linear head.
// fp32 end-to-end. CSR-by-dst built on device each launch (deterministic work).
// R1: hierarchical scan. R2: register-tiled transform GEMM.
// R3: parallel pool (was 68us latency-bound: 64 blocks, serial 195-deep chain).
// ---------------------------------------------------------------------------

__global__ __launch_bounds__(256) void init_counts_kernel(int* __restrict__ counts, int N) {
    int i = blockIdx.x * blockDim.x + threadIdx.x;
    if (i < N) counts[i] = 1;  // self-loop contributes 1 in-edge per node
}

__global__ __launch_bounds__(256) void count_kernel(const int* __restrict__ edst,
                                                    int* __restrict__ counts, int E) {
    int i = blockIdx.x * blockDim.x + threadIdx.x;
    if (i < E) atomicAdd(&counts[edst[i]], 1);
}

// --- hierarchical exclusive scan ----------------------------------------------
__global__ __launch_bounds__(256) void block_sum_kernel(const int* __restrict__ counts,
                                                        int* __restrict__ bsum, int N) {
    int i = blockIdx.x * 256 + threadIdx.x;
    int v = (i < N) ? counts[i] : 0;
#pragma unroll
    for (int o = 32; o > 0; o >>= 1) v += __shfl_xor(v, o, 64);
    __shared__ int wsum[4];
    if ((threadIdx.x & 63) == 0) wsum[threadIdx.x >> 6] = v;
    __syncthreads();
    if (threadIdx.x == 0) bsum[blockIdx.x] = wsum[0] + wsum[1] + wsum[2] + wsum[3];
}

__global__ __launch_bounds__(256) void scan_bsum_kernel(const int* __restrict__ bsum,
                                                        int* __restrict__ boff, int nb) {
    __shared__ int buf[256];
    int t = threadIdx.x;
    int v = (t < nb) ? bsum[t] : 0;
    buf[t] = v;
    __syncthreads();
    for (int o = 1; o < 256; o <<= 1) {
        int u = (t >= o) ? buf[t - o] : 0;
        __syncthreads();
        buf[t] += u;
        __syncthreads();
    }
    if (t < nb) boff[t] = buf[t] - v;
}

__global__ __launch_bounds__(256) void scan_final_kernel(const int* __restrict__ counts,
                                                         const int* __restrict__ boff,
                                                         int* __restrict__ row_start,
                                                         int* __restrict__ cursor, int N, int T) {
    __shared__ int buf[256];
    int t = threadIdx.x;
    int i = blockIdx.x * 256 + t;
    int v = (i < N) ? counts[i] : 0;
    buf[t] = v;
    __syncthreads();
    for (int o = 1; o < 256; o <<= 1) {
        int u = (t >= o) ? buf[t - o] : 0;
        __syncthreads();
        buf[t] += u;
        __syncthreads();
    }
    int excl = buf[t] - v + boff[blockIdx.x];
    if (i < N) { row_start[i] = excl; cursor[i] = excl; }
    if (i == N - 1) row_start[N] = T;
}
// -----------------------------------------------------------------------------

__global__ __launch_bounds__(256) void scatter_kernel(const int* __restrict__ esrc,
                                                      const int* __restrict__ edst,
                                                      int* __restrict__ cursor,
                                                      int* __restrict__ csr_src,
                                                      int E, int N) {
    int i = blockIdx.x * blockDim.x + threadIdx.x;
    int T = E + N;
    if (i >= T) return;
    int s, d;
    if (i < E) { s = esrc[i]; d = edst[i]; }
    else       { s = i - E;   d = s; }       // self loops appended after edges
    int pos = atomicAdd(&cursor[d], 1);
    csr_src[pos] = s;
}

// Layer 1: x is [N,1], W1 is [1,64] -> h[n][c] = X[n]*W1[c]; alpha dots collapse.
__global__ __launch_bounds__(256) void layer1_kernel(const float* __restrict__ X,
                                                     const float* __restrict__ W1,
                                                     const float* __restrict__ a_s,
                                                     const float* __restrict__ a_d,
                                                     float* __restrict__ h,
                                                     float* __restrict__ as,
                                                     float* __restrict__ ad, int N) {
    int lane = threadIdx.x & 63;
    int wave = threadIdx.x >> 6;
    int wpb  = blockDim.x >> 6;
    float w  = W1[lane];
    float da = w * a_s[lane];
    float db = w * a_d[lane];
#pragma unroll
    for (int o = 32; o > 0; o >>= 1) {
        da += __shfl_xor(da, o, 64);
        db += __shfl_xor(db, o, 64);
    }
    for (int n = blockIdx.x * wpb + wave; n < N; n += gridDim.x * wpb) {
        float xv = X[n];
        h[(size_t)n * 64 + lane] = xv * w;
        if (lane == 0) { as[n] = xv * da; ad[n] = xv * db; }
    }
}

// Layers 2..5 transform: register-tiled GEMM. 64-node tile/block, 256 threads,
// each thread computes 4 nodes x 4 channels. x tile staged TRANSPOSED in LDS.
__global__ __launch_bounds__(256) void transform_kernel(const float* __restrict__ x,
                                                        const float* __restrict__ W,
                                                        const float* __restrict__ a_s,
                                                        const float* __restrict__ a_d,
                                                        float* __restrict__ h,
                                                        float* __restrict__ as,
                                                        float* __restrict__ ad, int N) {
    __shared__ float Wl[64 * 64];
    __shared__ float xT[64 * 68];   // [k][n], stride 68 (mult of 4 -> b128-aligned)
    int t    = threadIdx.x;
    int lane = t & 63;
    int wv   = t >> 6;
    int base = blockIdx.x * 64;

    for (int i = t; i < 64 * 64; i += 256) Wl[i] = W[i];
#pragma unroll
    for (int r = 0; r < 16; ++r) {          // wave wv stages nodes wv*16..wv*16+15
        int nl = wv * 16 + r;
        int n  = base + nl;
        float v = (n < N) ? x[(size_t)n * 64 + lane] : 0.f;
        xT[lane * 68 + nl] = v;             // transpose: k=lane
    }
    __syncthreads();

    int c0  = (t & 15) * 4;                 // 4 output channels
    int nl0 = (t >> 4) * 4;                 // 4 nodes
    float acc[4][4] = {{0.f}};
#pragma unroll 8
    for (int k = 0; k < 64; ++k) {
        float4 xv = *reinterpret_cast<const float4*>(&xT[k * 68 + nl0]);
        float4 wl = *reinterpret_cast<const float4*>(&Wl[k * 64 + c0]);
        acc[0][0] = fmaf(xv.x, wl.x, acc[0][0]);
        acc[0][1] = fmaf(xv.x, wl.y, acc[0][1]);
        acc[0][2] = fmaf(xv.x, wl.z, acc[0][2]);
        acc[0][3] = fmaf(xv.x, wl.w, acc[0][3]);
        acc[1][0] = fmaf(xv.y, wl.x, acc[1][0]);
        acc[1][1] = fmaf(xv.y, wl.y, acc[1][1]);
        acc[1][2] = fmaf(xv.y, wl.z, acc[1][2]);
        acc[1][3] = fmaf(xv.y, wl.w, acc[1][3]);
        acc[2][0] = fmaf(xv.z, wl.x, acc[2][0]);
        acc[2][1] = fmaf(xv.z, wl.y, acc[2][1]);
        acc[2][2] = fmaf(xv.z, wl.z, acc[2][2]);
        acc[2][3] = fmaf(xv.z, wl.w, acc[2][3]);
        acc[3][0] = fmaf(xv.w, wl.x, acc[3][0]);
        acc[3][1] = fmaf(xv.w, wl.y, acc[3][1]);
        acc[3][2] = fmaf(xv.w, wl.z, acc[3][2]);
        acc[3][3] = fmaf(xv.w, wl.w, acc[3][3]);
    }

    float4 asv = *reinterpret_cast<const float4*>(&a_s[c0]);
    float4 adv = *reinterpret_cast<const float4*>(&a_d[c0]);
#pragma unroll
    for (int i = 0; i < 4; ++i) {
        int n = base + nl0 + i;
        if (n < N) {
            float4 o = make_float4(acc[i][0], acc[i][1], acc[i][2], acc[i][3]);
            *reinterpret_cast<float4*>(&h[(size_t)n * 64 + c0]) = o;
        }
        float s1 = acc[i][0] * asv.x + acc[i][1] * asv.y + acc[i][2] * asv.z + acc[i][3] * asv.w;
        float s2 = acc[i][0] * adv.x + acc[i][1] * adv.y + acc[i][2] * adv.z + acc[i][3] * adv.w;
#pragma unroll
        for (int o = 8; o > 0; o >>= 1) {
            s1 += __shfl_xor(s1, o, 64);
            s2 += __shfl_xor(s2, o, 64);
        }
        if ((lane & 15) == 0 && n < N) { as[n] = s1; ad[n] = s2; }
    }
}

// Per-dst-node softmax + weighted sum over in-edges; fused bias+ReLU+BN epilogue.
// One wave per node, lane = channel. Pass 2 unrolled x4 for gather ILP.
__global__ __launch_bounds__(256) void aggregate_kernel(const float* __restrict__ h,
                                                        const float* __restrict__ as,
                                                        const float* __restrict__ ad,
                                                        const int* __restrict__ row_start,
                                                        const int* __restrict__ csr_src,
                                                        const float* __restrict__ bias,
                                                        const float* __restrict__ gamma,
                                                        const float* __restrict__ beta,
                                                        const float* __restrict__ mean,
                                                        const float* __restrict__ var,
                                                        float* __restrict__ xout, int N) {
    int lane = threadIdx.x & 63;
    int wave = threadIdx.x >> 6;
    int wpb  = blockDim.x >> 6;
    float bc    = bias[lane];
    float scale = gamma[lane] * rsqrtf(var[lane] + 1e-5f);
    float shift = beta[lane] - mean[lane] * scale;
    for (int d = blockIdx.x * wpb + wave; d < N; d += gridDim.x * wpb) {
        int rs = row_start[d], re = row_start[d + 1];
        float add = ad[d];
        // pass 1: segment max (lanes parallel over edges)
        float m = -INFINITY;
        for (int j = rs + lane; j < re; j += 64) {
            int s   = csr_src[j];
            float e = as[s] + add;
            e = (e > 0.f) ? e : 0.2f * e;
            m = fmaxf(m, e);
        }
#pragma unroll
        for (int o = 32; o > 0; o >>= 1) m = fmaxf(m, __shfl_xor(m, o, 64));
        // pass 2: exp-sum + weighted gather of h[src], 4-wide for load ILP
        float z = 0.f, acc = 0.f;
        int j = rs;
        for (; j + 4 <= re; j += 4) {
            int s0 = csr_src[j + 0], s1 = csr_src[j + 1];
            int s2 = csr_src[j + 2], s3 = csr_src[j + 3];
            float a0 = as[s0], a1 = as[s1], a2 = as[s2], a3 = as[s3];
            float h0 = h[(size_t)s0 * 64 + lane], h1 = h[(size_t)s1 * 64 + lane];
            float h2 = h[(size_t)s2 * 64 + lane], h3 = h[(size_t)s3 * 64 + lane];
            float e0 = a0 + add; e0 = (e0 > 0.f) ? e0 : 0.2f * e0;
            float e1 = a1 + add; e1 = (e1 > 0.f) ? e1 : 0.2f * e1;
            float e2 = a2 + add; e2 = (e2 > 0.f) ? e2 : 0.2f * e2;
            float e3 = a3 + add; e3 = (e3 > 0.f) ? e3 : 0.2f * e3;
            float w0 = __expf(e0 - m), w1 = __expf(e1 - m);
            float w2 = __expf(e2 - m), w3 = __expf(e3 - m);
            z += (w0 + w1) + (w2 + w3);
            acc = fmaf(h0, w0, acc);
            acc = fmaf(h1, w1, acc);
            acc = fmaf(h2, w2, acc);
            acc = fmaf(h3, w3, acc);
        }
        for (; j < re; ++j) {
            int s   = csr_src[j];
            float e = as[s] + add;
            e = (e > 0.f) ? e : 0.2f * e;
            float w = __expf(e - m);
            z += w;
            acc = fmaf(h[(size_t)s * 64 + lane], w, acc);
        }
        float o = acc / z + bc;
        o = fmaxf(o, 0.f);                       // ReLU
        xout[(size_t)d * 64 + lane] = fmaf(o, scale, shift);  // BN (eval)
    }
}

__global__ __launch_bounds__(256) void gcount_kernel(const int* __restrict__ batch,
                                                     int* __restrict__ gcnt, int N) {
    int i = blockIdx.x * blockDim.x + threadIdx.x;
    if (i < N) atomicAdd(&gcnt[batch[i]], 1);
}

__global__ __launch_bounds__(256) void gscan_kernel(const int* __restrict__ gcnt,
                                                    int* __restrict__ gstart, int G) {
    __shared__ int buf[256];
    int t = threadIdx.x;
    buf[t] = (t < G) ? gcnt[t] : 0;
    __syncthreads();
    for (int off = 1; off < 256; off <<= 1) {
        int v = (t >= off) ? buf[t - off] : 0;
        __syncthreads();
        buf[t] += v;
        __syncthreads();
    }
    if (t < G) gstart[t] = buf[t] - gcnt[t];  // exclusive
}

// R3: one block (4 waves) per graph; each wave strides its graph's node range
// with 4 independent accumulators (16 loads in flight/block); LDS cross-wave
// combine; wave 0 writes pooled + linear head. Static assignment -> deterministic.
__global__ __launch_bounds__(256) void pool_kernel(const float* __restrict__ x,
                                                   const int* __restrict__ gstart,
                                                   const int* __restrict__ gcnt,
                                                   const float* __restrict__ Wr,
                                                   const float* __restrict__ br,
                                                   float* __restrict__ out, int G) {
    __shared__ float wsum[4][64];
    int lane = threadIdx.x & 63;
    int wv   = threadIdx.x >> 6;
    int g    = blockIdx.x;
    if (g >= G) return;
    int s = gstart[g], cnt = gcnt[g];
    float a0 = 0.f, a1 = 0.f, a2 = 0.f, a3 = 0.f;
    for (int r = wv * 4; r < cnt; r += 16) {
        const float* row = x + (size_t)(s + r) * 64 + lane;
        a0 += row[0];
        if (r + 1 < cnt) a1 += row[64];
        if (r + 2 < cnt) a2 += row[128];
        if (r + 3 < cnt) a3 += row[192];
    }
    wsum[wv][lane] = (a0 + a1) + (a2 + a3);
    __syncthreads();
    if (wv == 0) {
        float tot = (wsum[0][lane] + wsum[1][lane]) + (wsum[2][lane] + wsum[3][lane]);
        float pooled = tot / fmaxf((float)cnt, 1.f);
        out[G + (size_t)g * 64 + lane] = pooled;
        float p = pooled * Wr[lane];
#pragma unroll
        for (int o = 32; o > 0; o >>= 1) p += __shfl_xor(p, o, 64);
        if (lane == 0) out[g] = p + br[0];
    }
}

extern "C" void kernel_launch(void* const* d_in, const int* in_sizes, int n_in,
                              void* d_out, int out_size, void* d_ws, size_t ws_size,
                              hipStream_t stream) {
    const float* X        = (const float*)d_in[0];
    const int*   ei       = (const int*)d_in[1];
    const int*   batch    = (const int*)d_in[2];
    const float* W1       = (const float*)d_in[3];
    const float* Ws       = (const float*)d_in[4];
    const float* att_src  = (const float*)d_in[5];
    const float* att_dst  = (const float*)d_in[6];
    const float* bias     = (const float*)d_in[7];
    const float* bn_gamma = (const float*)d_in[8];
    const float* bn_beta  = (const float*)d_in[9];
    const float* bn_mean  = (const float*)d_in[10];
    const float* bn_var   = (const float*)d_in[11];
    const float* Wr       = (const float*)d_in[12];
    const float* br       = (const float*)d_in[13];

    const int N = in_sizes[0];        // IN == 1
    const int E = in_sizes[1] / 2;
    const int G = out_size / 65;      // pred[G] + pooled[G*64]

    // workspace carve-up (256B aligned)
    char* ws = (char*)d_ws;
    size_t off = 0;
    auto take = [&](size_t bytes) {
        void* p = ws + off;
        off = (off + bytes + 255) & ~(size_t)255;
        return p;
    };
    int nb = (N + 255) / 256;         // scan blocks (196 for N=50000, must be <=256)
    int*   counts    = (int*)take(sizeof(int) * N);
    int*   cursor    = (int*)take(sizeof(int) * N);
    int*   row_start = (int*)take(sizeof(int) * (N + 1));
    int*   csr_src   = (int*)take(sizeof(int) * (E + N));
    float* as        = (float*)take(sizeof(float) * N);
    float* ad        = (float*)take(sizeof(float) * N);
    float* h         = (float*)take(sizeof(float) * (size_t)N * 64);
    float* xa        = (float*)take(sizeof(float) * (size_t)N * 64);
    float* xb        = (float*)take(sizeof(float) * (size_t)N * 64);
    int*   gcnt      = (int*)take(sizeof(int) * G);
    int*   gstart    = (int*)take(sizeof(int) * G);
    int*   bsum      = (int*)take(sizeof(int) * nb);
    int*   boff      = (int*)take(sizeof(int) * nb);
    (void)ws_size;

    const int* esrc = ei;
    const int* edst = ei + E;

    hipMemsetAsync(gcnt, 0, sizeof(int) * G, stream);

    int nbN = (N + 255) / 256;
    init_counts_kernel<<<nbN, 256, 0, stream>>>(counts, N);
    count_kernel<<<(E + 255) / 256, 256, 0, stream>>>(edst, counts, E);
    block_sum_kernel<<<nb, 256, 0, stream>>>(counts, bsum, N);
    scan_bsum_kernel<<<1, 256, 0, stream>>>(bsum, boff, nb);
    scan_final_kernel<<<nb, 256, 0, stream>>>(counts, boff, row_start, cursor, N, E + N);
    scatter_kernel<<<(E + N + 255) / 256, 256, 0, stream>>>(esrc, edst, cursor, csr_src, E, N);

    int wb  = (N + 3) / 4;   // aggregate: 4 waves (nodes) per 256-thread block
    int tb  = (N + 63) / 64; // transform: 64-node tiles
    layer1_kernel<<<wb, 256, 0, stream>>>(X, W1, att_src, att_dst, h, as, ad, N);
    aggregate_kernel<<<wb, 256, 0, stream>>>(h, as, ad, row_start, csr_src,
                                             bias, bn_gamma, bn_beta, bn_mean, bn_var, xa, N);
    float* xin = xa;
    float* xout = xb;
    for (int L = 1; L < 5; ++L) {
        transform_kernel<<<tb, 256, 0, stream>>>(xin, Ws + (size_t)(L - 1) * 64 * 64,
                                                 att_src + (size_t)L * 64, att_dst + (size_t)L * 64,
                                                 h, as, ad, N);
        aggregate_kernel<<<wb, 256, 0, stream>>>(h, as, ad, row_start, csr_src,
                                                 bias + (size_t)L * 64, bn_gamma + (size_t)L * 64,
                                                 bn_beta + (size_t)L * 64, bn_mean + (size_t)L * 64,
                                                 bn_var + (size_t)L * 64, xout, N);
        float* t = xin; xin = xout; xout = t;
    }

    gcount_kernel<<<nbN, 256, 0, stream>>>(batch, gcnt, N);
    gscan_kernel<<<1, 256, 0, stream>>>(gcnt, gstart, G);
    pool_kernel<<<G, 256, 0, stream>>>(xin, gstart, gcnt, Wr, br, (float*)d_out, G);
}

// Round 5
// 449.530 us; speedup vs baseline: 2.4037x; 1.1377x over previous
//
#include <hip/hip_runtime.h>
#include <math.h>

// ---------------------------------------------------------------------------
// GAT regression: 5x (GATConv -> ReLU -> BN) -> mean pool -> linear head.
// fp32 end-to-end. CSR-by-dst built on device each launch (deterministic work).
// R1: hierarchical scan. R2: register-tiled transform GEMM. R3: parallel pool.
// R4: graph boundaries via sorted-batch scan (gcount was 63us atomic-bound).
// ---------------------------------------------------------------------------

__global__ __launch_bounds__(256) void init_counts_kernel(int* __restrict__ counts, int N) {
    int i = blockIdx.x * blockDim.x + threadIdx.x;
    if (i < N) counts[i] = 1;  // self-loop contributes 1 in-edge per node
}

__global__ __launch_bounds__(256) void count_kernel(const int* __restrict__ edst,
                                                    int* __restrict__ counts, int E) {
    int i = blockIdx.x * blockDim.x + threadIdx.x;
    if (i < E) atomicAdd(&counts[edst[i]], 1);
}

// --- hierarchical exclusive scan ----------------------------------------------
__global__ __launch_bounds__(256) void block_sum_kernel(const int* __restrict__ counts,
                                                        int* __restrict__ bsum, int N) {
    int i = blockIdx.x * 256 + threadIdx.x;
    int v = (i < N) ? counts[i] : 0;
#pragma unroll
    for (int o = 32; o > 0; o >>= 1) v += __shfl_xor(v, o, 64);
    __shared__ int wsum[4];
    if ((threadIdx.x & 63) == 0) wsum[threadIdx.x >> 6] = v;
    __syncthreads();
    if (threadIdx.x == 0) bsum[blockIdx.x] = wsum[0] + wsum[1] + wsum[2] + wsum[3];
}

__global__ __launch_bounds__(256) void scan_bsum_kernel(const int* __restrict__ bsum,
                                                        int* __restrict__ boff, int nb) {
    __shared__ int buf[256];
    int t = threadIdx.x;
    int v = (t < nb) ? bsum[t] : 0;
    buf[t] = v;
    __syncthreads();
    for (int o = 1; o < 256; o <<= 1) {
        int u = (t >= o) ? buf[t - o] : 0;
        __syncthreads();
        buf[t] += u;
        __syncthreads();
    }
    if (t < nb) boff[t] = buf[t] - v;
}

__global__ __launch_bounds__(256) void scan_final_kernel(const int* __restrict__ counts,
                                                         const int* __restrict__ boff,
                                                         int* __restrict__ row_start,
                                                         int* __restrict__ cursor, int N, int T) {
    __shared__ int buf[256];
    int t = threadIdx.x;
    int i = blockIdx.x * 256 + t;
    int v = (i < N) ? counts[i] : 0;
    buf[t] = v;
    __syncthreads();
    for (int o = 1; o < 256; o <<= 1) {
        int u = (t >= o) ? buf[t - o] : 0;
        __syncthreads();
        buf[t] += u;
        __syncthreads();
    }
    int excl = buf[t] - v + boff[blockIdx.x];
    if (i < N) { row_start[i] = excl; cursor[i] = excl; }
    if (i == N - 1) row_start[N] = T;
}
// -----------------------------------------------------------------------------

__global__ __launch_bounds__(256) void scatter_kernel(const int* __restrict__ esrc,
                                                      const int* __restrict__ edst,
                                                      int* __restrict__ cursor,
                                                      int* __restrict__ csr_src,
                                                      int E, int N) {
    int i = blockIdx.x * blockDim.x + threadIdx.x;
    int T = E + N;
    if (i >= T) return;
    int s, d;
    if (i < E) { s = esrc[i]; d = edst[i]; }
    else       { s = i - E;   d = s; }       // self loops appended after edges
    int pos = atomicAdd(&cursor[d], 1);
    csr_src[pos] = s;
}

// Layer 1: x is [N,1], W1 is [1,64] -> h[n][c] = X[n]*W1[c]; alpha dots collapse.
__global__ __launch_bounds__(256) void layer1_kernel(const float* __restrict__ X,
                                                     const float* __restrict__ W1,
                                                     const float* __restrict__ a_s,
                                                     const float* __restrict__ a_d,
                                                     float* __restrict__ h,
                                                     float* __restrict__ as,
                                                     float* __restrict__ ad, int N) {
    int lane = threadIdx.x & 63;
    int wave = threadIdx.x >> 6;
    int wpb  = blockDim.x >> 6;
    float w  = W1[lane];
    float da = w * a_s[lane];
    float db = w * a_d[lane];
#pragma unroll
    for (int o = 32; o > 0; o >>= 1) {
        da += __shfl_xor(da, o, 64);
        db += __shfl_xor(db, o, 64);
    }
    for (int n = blockIdx.x * wpb + wave; n < N; n += gridDim.x * wpb) {
        float xv = X[n];
        h[(size_t)n * 64 + lane] = xv * w;
        if (lane == 0) { as[n] = xv * da; ad[n] = xv * db; }
    }
}

// Layers 2..5 transform: register-tiled GEMM. 64-node tile/block, 256 threads,
// each thread computes 4 nodes x 4 channels. x tile staged TRANSPOSED in LDS.
__global__ __launch_bounds__(256) void transform_kernel(const float* __restrict__ x,
                                                        const float* __restrict__ W,
                                                        const float* __restrict__ a_s,
                                                        const float* __restrict__ a_d,
                                                        float* __restrict__ h,
                                                        float* __restrict__ as,
                                                        float* __restrict__ ad, int N) {
    __shared__ float Wl[64 * 64];
    __shared__ float xT[64 * 68];   // [k][n], stride 68 (mult of 4 -> b128-aligned)
    int t    = threadIdx.x;
    int lane = t & 63;
    int wv   = t >> 6;
    int base = blockIdx.x * 64;

    for (int i = t; i < 64 * 64; i += 256) Wl[i] = W[i];
#pragma unroll
    for (int r = 0; r < 16; ++r) {          // wave wv stages nodes wv*16..wv*16+15
        int nl = wv * 16 + r;
        int n  = base + nl;
        float v = (n < N) ? x[(size_t)n * 64 + lane] : 0.f;
        xT[lane * 68 + nl] = v;             // transpose: k=lane
    }
    __syncthreads();

    int c0  = (t & 15) * 4;                 // 4 output channels
    int nl0 = (t >> 4) * 4;                 // 4 nodes
    float acc[4][4] = {{0.f}};
#pragma unroll 8
    for (int k = 0; k < 64; ++k) {
        float4 xv = *reinterpret_cast<const float4*>(&xT[k * 68 + nl0]);
        float4 wl = *reinterpret_cast<const float4*>(&Wl[k * 64 + c0]);
        acc[0][0] = fmaf(xv.x, wl.x, acc[0][0]);
        acc[0][1] = fmaf(xv.x, wl.y, acc[0][1]);
        acc[0][2] = fmaf(xv.x, wl.z, acc[0][2]);
        acc[0][3] = fmaf(xv.x, wl.w, acc[0][3]);
        acc[1][0] = fmaf(xv.y, wl.x, acc[1][0]);
        acc[1][1] = fmaf(xv.y, wl.y, acc[1][1]);
        acc[1][2] = fmaf(xv.y, wl.z, acc[1][2]);
        acc[1][3] = fmaf(xv.y, wl.w, acc[1][3]);
        acc[2][0] = fmaf(xv.z, wl.x, acc[2][0]);
        acc[2][1] = fmaf(xv.z, wl.y, acc[2][1]);
        acc[2][2] = fmaf(xv.z, wl.z, acc[2][2]);
        acc[2][3] = fmaf(xv.z, wl.w, acc[2][3]);
        acc[3][0] = fmaf(xv.w, wl.x, acc[3][0]);
        acc[3][1] = fmaf(xv.w, wl.y, acc[3][1]);
        acc[3][2] = fmaf(xv.w, wl.z, acc[3][2]);
        acc[3][3] = fmaf(xv.w, wl.w, acc[3][3]);
    }

    float4 asv = *reinterpret_cast<const float4*>(&a_s[c0]);
    float4 adv = *reinterpret_cast<const float4*>(&a_d[c0]);
#pragma unroll
    for (int i = 0; i < 4; ++i) {
        int n = base + nl0 + i;
        if (n < N) {
            float4 o = make_float4(acc[i][0], acc[i][1], acc[i][2], acc[i][3]);
            *reinterpret_cast<float4*>(&h[(size_t)n * 64 + c0]) = o;
        }
        float s1 = acc[i][0] * asv.x + acc[i][1] * asv.y + acc[i][2] * asv.z + acc[i][3] * asv.w;
        float s2 = acc[i][0] * adv.x + acc[i][1] * adv.y + acc[i][2] * adv.z + acc[i][3] * adv.w;
#pragma unroll
        for (int o = 8; o > 0; o >>= 1) {
            s1 += __shfl_xor(s1, o, 64);
            s2 += __shfl_xor(s2, o, 64);
        }
        if ((lane & 15) == 0 && n < N) { as[n] = s1; ad[n] = s2; }
    }
}

// Per-dst-node softmax + weighted sum over in-edges; fused bias+ReLU+BN epilogue.
// One wave per node, lane = channel. Pass 2 unrolled x4 for gather ILP.
__global__ __launch_bounds__(256) void aggregate_kernel(const float* __restrict__ h,
                                                        const float* __restrict__ as,
                                                        const float* __restrict__ ad,
                                                        const int* __restrict__ row_start,
                                                        const int* __restrict__ csr_src,
                                                        const float* __restrict__ bias,
                                                        const float* __restrict__ gamma,
                                                        const float* __restrict__ beta,
                                                        const float* __restrict__ mean,
                                                        const float* __restrict__ var,
                                                        float* __restrict__ xout, int N) {
    int lane = threadIdx.x & 63;
    int wave = threadIdx.x >> 6;
    int wpb  = blockDim.x >> 6;
    float bc    = bias[lane];
    float scale = gamma[lane] * rsqrtf(var[lane] + 1e-5f);
    float shift = beta[lane] - mean[lane] * scale;
    for (int d = blockIdx.x * wpb + wave; d < N; d += gridDim.x * wpb) {
        int rs = row_start[d], re = row_start[d + 1];
        float add = ad[d];
        // pass 1: segment max (lanes parallel over edges)
        float m = -INFINITY;
        for (int j = rs + lane; j < re; j += 64) {
            int s   = csr_src[j];
            float e = as[s] + add;
            e = (e > 0.f) ? e : 0.2f * e;
            m = fmaxf(m, e);
        }
#pragma unroll
        for (int o = 32; o > 0; o >>= 1) m = fmaxf(m, __shfl_xor(m, o, 64));
        // pass 2: exp-sum + weighted gather of h[src], 4-wide for load ILP
        float z = 0.f, acc = 0.f;
        int j = rs;
        for (; j + 4 <= re; j += 4) {
            int s0 = csr_src[j + 0], s1 = csr_src[j + 1];
            int s2 = csr_src[j + 2], s3 = csr_src[j + 3];
            float a0 = as[s0], a1 = as[s1], a2 = as[s2], a3 = as[s3];
            float h0 = h[(size_t)s0 * 64 + lane], h1 = h[(size_t)s1 * 64 + lane];
            float h2 = h[(size_t)s2 * 64 + lane], h3 = h[(size_t)s3 * 64 + lane];
            float e0 = a0 + add; e0 = (e0 > 0.f) ? e0 : 0.2f * e0;
            float e1 = a1 + add; e1 = (e1 > 0.f) ? e1 : 0.2f * e1;
            float e2 = a2 + add; e2 = (e2 > 0.f) ? e2 : 0.2f * e2;
            float e3 = a3 + add; e3 = (e3 > 0.f) ? e3 : 0.2f * e3;
            float w0 = __expf(e0 - m), w1 = __expf(e1 - m);
            float w2 = __expf(e2 - m), w3 = __expf(e3 - m);
            z += (w0 + w1) + (w2 + w3);
            acc = fmaf(h0, w0, acc);
            acc = fmaf(h1, w1, acc);
            acc = fmaf(h2, w2, acc);
            acc = fmaf(h3, w3, acc);
        }
        for (; j < re; ++j) {
            int s   = csr_src[j];
            float e = as[s] + add;
            e = (e > 0.f) ? e : 0.2f * e;
            float w = __expf(e - m);
            z += w;
            acc = fmaf(h[(size_t)s * 64 + lane], w, acc);
        }
        float o = acc / z + bc;
        o = fmaxf(o, 0.f);                       // ReLU
        xout[(size_t)d * 64 + lane] = fmaf(o, scale, shift);  // BN (eval)
    }
}

// R4: batch is sorted -> graph g's nodes are [gstart[g], gstart[g+1]).
// gstart[g] = first index i with batch[i] >= g; gstart[G] = N. No atomics.
__global__ __launch_bounds__(256) void gbounds_kernel(const int* __restrict__ batch,
                                                      int* __restrict__ gstart, int N, int G) {
    int i = blockIdx.x * blockDim.x + threadIdx.x;
    if (i > N) return;
    if (i == 0) {
        for (int g = 0; g <= batch[0]; ++g) gstart[g] = 0;
    } else if (i == N) {
        for (int g = batch[N - 1] + 1; g <= G; ++g) gstart[g] = N;
    } else {
        int b0 = batch[i - 1], b1 = batch[i];
        for (int g = b0 + 1; g <= b1; ++g) gstart[g] = i;
    }
}

// R3: one block (4 waves) per graph; 16 independent loads in flight per block;
// LDS cross-wave combine; wave 0 writes pooled + linear head.
__global__ __launch_bounds__(256) void pool_kernel(const float* __restrict__ x,
                                                   const int* __restrict__ gstart,
                                                   const float* __restrict__ Wr,
                                                   const float* __restrict__ br,
                                                   float* __restrict__ out, int G) {
    __shared__ float wsum[4][64];
    int lane = threadIdx.x & 63;
    int wv   = threadIdx.x >> 6;
    int g    = blockIdx.x;
    if (g >= G) return;
    int s = gstart[g], cnt = gstart[g + 1] - s;
    float a0 = 0.f, a1 = 0.f, a2 = 0.f, a3 = 0.f;
    for (int r = wv * 4; r < cnt; r += 16) {
        const float* row = x + (size_t)(s + r) * 64 + lane;
        a0 += row[0];
        if (r + 1 < cnt) a1 += row[64];
        if (r + 2 < cnt) a2 += row[128];
        if (r + 3 < cnt) a3 += row[192];
    }
    wsum[wv][lane] = (a0 + a1) + (a2 + a3);
    __syncthreads();
    if (wv == 0) {
        float tot = (wsum[0][lane] + wsum[1][lane]) + (wsum[2][lane] + wsum[3][lane]);
        float pooled = tot / fmaxf((float)cnt, 1.f);
        out[G + (size_t)g * 64 + lane] = pooled;
        float p = pooled * Wr[lane];
#pragma unroll
        for (int o = 32; o > 0; o >>= 1) p += __shfl_xor(p, o, 64);
        if (lane == 0) out[g] = p + br[0];
    }
}

extern "C" void kernel_launch(void* const* d_in, const int* in_sizes, int n_in,
                              void* d_out, int out_size, void* d_ws, size_t ws_size,
                              hipStream_t stream) {
    const float* X        = (const float*)d_in[0];
    const int*   ei       = (const int*)d_in[1];
    const int*   batch    = (const int*)d_in[2];
    const float* W1       = (const float*)d_in[3];
    const float* Ws       = (const float*)d_in[4];
    const float* att_src  = (const float*)d_in[5];
    const float* att_dst  = (const float*)d_in[6];
    const float* bias     = (const float*)d_in[7];
    const float* bn_gamma = (const float*)d_in[8];
    const float* bn_beta  = (const float*)d_in[9];
    const float* bn_mean  = (const float*)d_in[10];
    const float* bn_var   = (const float*)d_in[11];
    const float* Wr       = (const float*)d_in[12];
    const float* br       = (const float*)d_in[13];

    const int N = in_sizes[0];        // IN == 1
    const int E = in_sizes[1] / 2;
    const int G = out_size / 65;      // pred[G] + pooled[G*64]

    // workspace carve-up (256B aligned)
    char* ws = (char*)d_ws;
    size_t off = 0;
    auto take = [&](size_t bytes) {
        void* p = ws + off;
        off = (off + bytes + 255) & ~(size_t)255;
        return p;
    };
    int nb = (N + 255) / 256;         // scan blocks (196 for N=50000, must be <=256)
    int*   counts    = (int*)take(sizeof(int) * N);
    int*   cursor    = (int*)take(sizeof(int) * N);
    int*   row_start = (int*)take(sizeof(int) * (N + 1));
    int*   csr_src   = (int*)take(sizeof(int) * (E + N));
    float* as        = (float*)take(sizeof(float) * N);
    float* ad        = (float*)take(sizeof(float) * N);
    float* h         = (float*)take(sizeof(float) * (size_t)N * 64);
    float* xa        = (float*)take(sizeof(float) * (size_t)N * 64);
    float* xb        = (float*)take(sizeof(float) * (size_t)N * 64);
    int*   gstart    = (int*)take(sizeof(int) * (G + 1));
    int*   bsum      = (int*)take(sizeof(int) * nb);
    int*   boff      = (int*)take(sizeof(int) * nb);
    (void)ws_size;

    const int* esrc = ei;
    const int* edst = ei + E;

    int nbN = (N + 255) / 256;
    init_counts_kernel<<<nbN, 256, 0, stream>>>(counts, N);
    count_kernel<<<(E + 255) / 256, 256, 0, stream>>>(edst, counts, E);
    block_sum_kernel<<<nb, 256, 0, stream>>>(counts, bsum, N);
    scan_bsum_kernel<<<1, 256, 0, stream>>>(bsum, boff, nb);
    scan_final_kernel<<<nb, 256, 0, stream>>>(counts, boff, row_start, cursor, N, E + N);
    scatter_kernel<<<(E + N + 255) / 256, 256, 0, stream>>>(esrc, edst, cursor, csr_src, E, N);

    int wb  = (N + 3) / 4;   // aggregate: 4 waves (nodes) per 256-thread block
    int tb  = (N + 63) / 64; // transform: 64-node tiles
    layer1_kernel<<<wb, 256, 0, stream>>>(X, W1, att_src, att_dst, h, as, ad, N);
    aggregate_kernel<<<wb, 256, 0, stream>>>(h, as, ad, row_start, csr_src,
                                             bias, bn_gamma, bn_beta, bn_mean, bn_var, xa, N);
    float* xin = xa;
    float* xout = xb;
    for (int L = 1; L < 5; ++L) {
        transform_kernel<<<tb, 256, 0, stream>>>(xin, Ws + (size_t)(L - 1) * 64 * 64,
                                                 att_src + (size_t)L * 64, att_dst + (size_t)L * 64,
                                                 h, as, ad, N);
        aggregate_kernel<<<wb, 256, 0, stream>>>(h, as, ad, row_start, csr_src,
                                                 bias + (size_t)L * 64, bn_gamma + (size_t)L * 64,
                                                 bn_beta + (size_t)L * 64, bn_mean + (size_t)L * 64,
                                                 bn_var + (size_t)L * 64, xout, N);
        float* t = xin; xin = xout; xout = t;
    }

    gbounds_kernel<<<(N + 256) / 256, 256, 0, stream>>>(batch, gstart, N, G);
    pool_kernel<<<G, 256, 0, stream>>>(xin, gstart, Wr, br, (float*)d_out, G);
}

// Round 6
// 419.636 us; speedup vs baseline: 2.5750x; 1.0712x over previous
//
#include <hip/hip_runtime.h>
#include <math.h>

// ---------------------------------------------------------------------------
// GAT regression: 5x (GATConv -> ReLU -> BN) -> mean pool -> linear head.
// fp32 end-to-end. CSR-by-dst built on device each launch (deterministic work).
// R1: hierarchical scan. R2: register-tiled transform GEMM. R3: parallel pool.
// R4: graph bounds from sorted batch. R5: LDS-staged bucket sort for CSR build
//     (old scatter: 54MB writeback = 1 full line per 4B random write, 57us).
// ---------------------------------------------------------------------------

#define CH  4096   // edges per phase-1 chunk
#define CAP 6144   // phase-2 LDS csr capacity (avg bucket ~4350, 27-sigma safe)

__global__ __launch_bounds__(256) void init_counts_kernel(int* __restrict__ counts, int N) {
    int i = blockIdx.x * blockDim.x + threadIdx.x;
    if (i < N) counts[i] = 1;  // self-loop contributes 1 in-edge per node
}

__global__ __launch_bounds__(256) void count_kernel(const int* __restrict__ edst,
                                                    int* __restrict__ counts, int E) {
    int i = blockIdx.x * blockDim.x + threadIdx.x;
    if (i < E) atomicAdd(&counts[edst[i]], 1);
}

// --- hierarchical exclusive scan ----------------------------------------------
__global__ __launch_bounds__(256) void block_sum_kernel(const int* __restrict__ counts,
                                                        int* __restrict__ bsum, int N) {
    int i = blockIdx.x * 256 + threadIdx.x;
    int v = (i < N) ? counts[i] : 0;
#pragma unroll
    for (int o = 32; o > 0; o >>= 1) v += __shfl_xor(v, o, 64);
    __shared__ int wsum[4];
    if ((threadIdx.x & 63) == 0) wsum[threadIdx.x >> 6] = v;
    __syncthreads();
    if (threadIdx.x == 0) bsum[blockIdx.x] = wsum[0] + wsum[1] + wsum[2] + wsum[3];
}

__global__ __launch_bounds__(256) void scan_bsum_kernel(const int* __restrict__ bsum,
                                                        int* __restrict__ boff, int nb) {
    __shared__ int buf[256];
    int t = threadIdx.x;
    int v = (t < nb) ? bsum[t] : 0;
    buf[t] = v;
    __syncthreads();
    for (int o = 1; o < 256; o <<= 1) {
        int u = (t >= o) ? buf[t - o] : 0;
        __syncthreads();
        buf[t] += u;
        __syncthreads();
    }
    if (t < nb) boff[t] = buf[t] - v;
}

__global__ __launch_bounds__(256) void scan_final_kernel(const int* __restrict__ counts,
                                                         const int* __restrict__ boff,
                                                         int* __restrict__ row_start,
                                                         int N, int T) {
    __shared__ int buf[256];
    int t = threadIdx.x;
    int i = blockIdx.x * 256 + t;
    int v = (i < N) ? counts[i] : 0;
    buf[t] = v;
    __syncthreads();
    for (int o = 1; o < 256; o <<= 1) {
        int u = (t >= o) ? buf[t - o] : 0;
        __syncthreads();
        buf[t] += u;
        __syncthreads();
    }
    int excl = buf[t] - v + boff[blockIdx.x];
    if (i < N) row_start[i] = excl;
    if (i == N - 1) row_start[N] = T;
}
// -----------------------------------------------------------------------------

// R5 phase 1: LDS-staged bucketing. Bucket = dst>>8 (256 nodes). Each block
// bins CH edges in LDS, reserves contiguous global chunks per bucket, and
// flushes coalesced runs into ebuf (bucket-partitioned, chunk-jumbled inside).
// Payload: (src<<8) | (dst&255) -- src < 2^24.
__global__ __launch_bounds__(256) void bucket_scatter_kernel(const int* __restrict__ esrc,
                                                             const int* __restrict__ edst,
                                                             const int* __restrict__ row_start,
                                                             int* __restrict__ bkt_cursor,
                                                             unsigned* __restrict__ ebuf,
                                                             int E, int N, int NB) {
    __shared__ unsigned buf[CH];
    __shared__ unsigned short bkt[CH];
    __shared__ int histA[256], base[256], curB[256], gofs[256];
    int t    = threadIdx.x;
    int T    = E + N;
    int c0   = blockIdx.x * CH;
    int cend = min(c0 + CH, T);
    int M    = cend - c0;
    histA[t] = 0;
    __syncthreads();
    // pass 1: count buckets in this chunk
    for (int i = c0 + t; i < cend; i += 256) {
        int d = (i < E) ? edst[i] : (i - E);
        atomicAdd(&histA[d >> 8], 1);
    }
    __syncthreads();
    int v = histA[t];
    base[t] = v;
    __syncthreads();
    for (int o = 1; o < 256; o <<= 1) {      // inclusive scan
        int u = (t >= o) ? base[t - o] : 0;
        __syncthreads();
        base[t] += u;
        __syncthreads();
    }
    int excl = base[t] - v;
    __syncthreads();
    base[t] = excl;
    curB[t] = excl;
    __syncthreads();
    // reserve global chunk per bucket (bucket region base = row_start[bkt<<8])
    if (t < NB && v > 0)
        gofs[t] = row_start[t << 8] + atomicAdd(&bkt_cursor[t], v);
    // pass 2: local scatter into LDS, ordered by bucket
    for (int i = c0 + t; i < cend; i += 256) {
        int s, d;
        if (i < E) { s = esrc[i]; d = edst[i]; }
        else       { s = i - E;   d = s; }
        int b = d >> 8;
        int r = atomicAdd(&curB[b], 1);
        buf[r] = ((unsigned)s << 8) | (unsigned)(d & 255);
        bkt[r] = (unsigned short)b;
    }
    __syncthreads();
    // flush: contiguous run per bucket -> coalesced global writes
    for (int i = t; i < M; i += 256) {
        int b = bkt[i];
        ebuf[gofs[b] + (i - base[b])] = buf[i];
    }
}

// R5 phase 2: per-bucket counting sort. One block per 256-node bucket; node
// cursors derived from row_start (no recount); scatter lands in LDS; final
// csr_src write is contiguous + coalesced.
__global__ __launch_bounds__(256) void bucket_sort_kernel(const unsigned* __restrict__ ebuf,
                                                          const int* __restrict__ row_start,
                                                          int* __restrict__ csr_src, int N) {
    __shared__ int cur[256];
    __shared__ int csr_lds[CAP];
    int t  = threadIdx.x;
    int n0 = blockIdx.x << 8;
    int n1 = min(n0 + 256, N);
    int rs = row_start[n0];
    int re = row_start[n1];
    int M  = re - rs;
    cur[t] = (n0 + t < n1) ? (row_start[n0 + t] - rs) : 0;
    __syncthreads();
    if (M <= CAP) {
        for (int i = t; i < M; i += 256) {
            unsigned v = ebuf[rs + i];
            int p = atomicAdd(&cur[v & 255u], 1);
            csr_lds[p] = (int)(v >> 8);
        }
        __syncthreads();
        for (int i = t; i < M; i += 256) csr_src[rs + i] = csr_lds[i];
    } else {  // overflow fallback (statistically unreachable, kept for safety)
        for (int i = t; i < M; i += 256) {
            unsigned v = ebuf[rs + i];
            int p = atomicAdd(&cur[v & 255u], 1);
            csr_src[rs + p] = (int)(v >> 8);
        }
    }
}

// Layer 1: x is [N,1], W1 is [1,64] -> h[n][c] = X[n]*W1[c]; alpha dots collapse.
__global__ __launch_bounds__(256) void layer1_kernel(const float* __restrict__ X,
                                                     const float* __restrict__ W1,
                                                     const float* __restrict__ a_s,
                                                     const float* __restrict__ a_d,
                                                     float* __restrict__ h,
                                                     float* __restrict__ as,
                                                     float* __restrict__ ad, int N) {
    int lane = threadIdx.x & 63;
    int wave = threadIdx.x >> 6;
    int wpb  = blockDim.x >> 6;
    float w  = W1[lane];
    float da = w * a_s[lane];
    float db = w * a_d[lane];
#pragma unroll
    for (int o = 32; o > 0; o >>= 1) {
        da += __shfl_xor(da, o, 64);
        db += __shfl_xor(db, o, 64);
    }
    for (int n = blockIdx.x * wpb + wave; n < N; n += gridDim.x * wpb) {
        float xv = X[n];
        h[(size_t)n * 64 + lane] = xv * w;
        if (lane == 0) { as[n] = xv * da; ad[n] = xv * db; }
    }
}

// Layers 2..5 transform: register-tiled GEMM. 64-node tile/block, 256 threads,
// each thread computes 4 nodes x 4 channels. x tile staged TRANSPOSED in LDS.
__global__ __launch_bounds__(256) void transform_kernel(const float* __restrict__ x,
                                                        const float* __restrict__ W,
                                                        const float* __restrict__ a_s,
                                                        const float* __restrict__ a_d,
                                                        float* __restrict__ h,
                                                        float* __restrict__ as,
                                                        float* __restrict__ ad, int N) {
    __shared__ float Wl[64 * 64];
    __shared__ float xT[64 * 68];   // [k][n], stride 68 (mult of 4 -> b128-aligned)
    int t    = threadIdx.x;
    int lane = t & 63;
    int wv   = t >> 6;
    int base = blockIdx.x * 64;

    for (int i = t; i < 64 * 64; i += 256) Wl[i] = W[i];
#pragma unroll
    for (int r = 0; r < 16; ++r) {
        int nl = wv * 16 + r;
        int n  = base + nl;
        float v = (n < N) ? x[(size_t)n * 64 + lane] : 0.f;
        xT[lane * 68 + nl] = v;
    }
    __syncthreads();

    int c0  = (t & 15) * 4;
    int nl0 = (t >> 4) * 4;
    float acc[4][4] = {{0.f}};
#pragma unroll 8
    for (int k = 0; k < 64; ++k) {
        float4 xv = *reinterpret_cast<const float4*>(&xT[k * 68 + nl0]);
        float4 wl = *reinterpret_cast<const float4*>(&Wl[k * 64 + c0]);
        acc[0][0] = fmaf(xv.x, wl.x, acc[0][0]);
        acc[0][1] = fmaf(xv.x, wl.y, acc[0][1]);
        acc[0][2] = fmaf(xv.x, wl.z, acc[0][2]);
        acc[0][3] = fmaf(xv.x, wl.w, acc[0][3]);
        acc[1][0] = fmaf(xv.y, wl.x, acc[1][0]);
        acc[1][1] = fmaf(xv.y, wl.y, acc[1][1]);
        acc[1][2] = fmaf(xv.y, wl.z, acc[1][2]);
        acc[1][3] = fmaf(xv.y, wl.w, acc[1][3]);
        acc[2][0] = fmaf(xv.z, wl.x, acc[2][0]);
        acc[2][1] = fmaf(xv.z, wl.y, acc[2][1]);
        acc[2][2] = fmaf(xv.z, wl.z, acc[2][2]);
        acc[2][3] = fmaf(xv.z, wl.w, acc[2][3]);
        acc[3][0] = fmaf(xv.w, wl.x, acc[3][0]);
        acc[3][1] = fmaf(xv.w, wl.y, acc[3][1]);
        acc[3][2] = fmaf(xv.w, wl.z, acc[3][2]);
        acc[3][3] = fmaf(xv.w, wl.w, acc[3][3]);
    }

    float4 asv = *reinterpret_cast<const float4*>(&a_s[c0]);
    float4 adv = *reinterpret_cast<const float4*>(&a_d[c0]);
#pragma unroll
    for (int i = 0; i < 4; ++i) {
        int n = base + nl0 + i;
        if (n < N) {
            float4 o = make_float4(acc[i][0], acc[i][1], acc[i][2], acc[i][3]);
            *reinterpret_cast<float4*>(&h[(size_t)n * 64 + c0]) = o;
        }
        float s1 = acc[i][0] * asv.x + acc[i][1] * asv.y + acc[i][2] * asv.z + acc[i][3] * asv.w;
        float s2 = acc[i][0] * adv.x + acc[i][1] * adv.y + acc[i][2] * adv.z + acc[i][3] * adv.w;
#pragma unroll
        for (int o = 8; o > 0; o >>= 1) {
            s1 += __shfl_xor(s1, o, 64);
            s2 += __shfl_xor(s2, o, 64);
        }
        if ((lane & 15) == 0 && n < N) { as[n] = s1; ad[n] = s2; }
    }
}

// Per-dst-node softmax + weighted sum over in-edges; fused bias+ReLU+BN epilogue.
__global__ __launch_bounds__(256) void aggregate_kernel(const float* __restrict__ h,
                                                        const float* __restrict__ as,
                                                        const float* __restrict__ ad,
                                                        const int* __restrict__ row_start,
                                                        const int* __restrict__ csr_src,
                                                        const float* __restrict__ bias,
                                                        const float* __restrict__ gamma,
                                                        const float* __restrict__ beta,
                                                        const float* __restrict__ mean,
                                                        const float* __restrict__ var,
                                                        float* __restrict__ xout, int N) {
    int lane = threadIdx.x & 63;
    int wave = threadIdx.x >> 6;
    int wpb  = blockDim.x >> 6;
    float bc    = bias[lane];
    float scale = gamma[lane] * rsqrtf(var[lane] + 1e-5f);
    float shift = beta[lane] - mean[lane] * scale;
    for (int d = blockIdx.x * wpb + wave; d < N; d += gridDim.x * wpb) {
        int rs = row_start[d], re = row_start[d + 1];
        float add = ad[d];
        float m = -INFINITY;
        for (int j = rs + lane; j < re; j += 64) {
            int s   = csr_src[j];
            float e = as[s] + add;
            e = (e > 0.f) ? e : 0.2f * e;
            m = fmaxf(m, e);
        }
#pragma unroll
        for (int o = 32; o > 0; o >>= 1) m = fmaxf(m, __shfl_xor(m, o, 64));
        float z = 0.f, acc = 0.f;
        int j = rs;
        for (; j + 4 <= re; j += 4) {
            int s0 = csr_src[j + 0], s1 = csr_src[j + 1];
            int s2 = csr_src[j + 2], s3 = csr_src[j + 3];
            float a0 = as[s0], a1 = as[s1], a2 = as[s2], a3 = as[s3];
            float h0 = h[(size_t)s0 * 64 + lane], h1 = h[(size_t)s1 * 64 + lane];
            float h2 = h[(size_t)s2 * 64 + lane], h3 = h[(size_t)s3 * 64 + lane];
            float e0 = a0 + add; e0 = (e0 > 0.f) ? e0 : 0.2f * e0;
            float e1 = a1 + add; e1 = (e1 > 0.f) ? e1 : 0.2f * e1;
            float e2 = a2 + add; e2 = (e2 > 0.f) ? e2 : 0.2f * e2;
            float e3 = a3 + add; e3 = (e3 > 0.f) ? e3 : 0.2f * e3;
            float w0 = __expf(e0 - m), w1 = __expf(e1 - m);
            float w2 = __expf(e2 - m), w3 = __expf(e3 - m);
            z += (w0 + w1) + (w2 + w3);
            acc = fmaf(h0, w0, acc);
            acc = fmaf(h1, w1, acc);
            acc = fmaf(h2, w2, acc);
            acc = fmaf(h3, w3, acc);
        }
        for (; j < re; ++j) {
            int s   = csr_src[j];
            float e = as[s] + add;
            e = (e > 0.f) ? e : 0.2f * e;
            float w = __expf(e - m);
            z += w;
            acc = fmaf(h[(size_t)s * 64 + lane], w, acc);
        }
        float o = acc / z + bc;
        o = fmaxf(o, 0.f);
        xout[(size_t)d * 64 + lane] = fmaf(o, scale, shift);
    }
}

// batch is sorted -> graph g's nodes are [gstart[g], gstart[g+1]).
__global__ __launch_bounds__(256) void gbounds_kernel(const int* __restrict__ batch,
                                                      int* __restrict__ gstart, int N, int G) {
    int i = blockIdx.x * blockDim.x + threadIdx.x;
    if (i > N) return;
    if (i == 0) {
        for (int g = 0; g <= batch[0]; ++g) gstart[g] = 0;
    } else if (i == N) {
        for (int g = batch[N - 1] + 1; g <= G; ++g) gstart[g] = N;
    } else {
        int b0 = batch[i - 1], b1 = batch[i];
        for (int g = b0 + 1; g <= b1; ++g) gstart[g] = i;
    }
}

// One block (4 waves) per graph; LDS cross-wave combine; wave 0 writes head.
__global__ __launch_bounds__(256) void pool_kernel(const float* __restrict__ x,
                                                   const int* __restrict__ gstart,
                                                   const float* __restrict__ Wr,
                                                   const float* __restrict__ br,
                                                   float* __restrict__ out, int G) {
    __shared__ float wsum[4][64];
    int lane = threadIdx.x & 63;
    int wv   = threadIdx.x >> 6;
    int g    = blockIdx.x;
    if (g >= G) return;
    int s = gstart[g], cnt = gstart[g + 1] - s;
    float a0 = 0.f, a1 = 0.f, a2 = 0.f, a3 = 0.f;
    for (int r = wv * 4; r < cnt; r += 16) {
        const float* row = x + (size_t)(s + r) * 64 + lane;
        a0 += row[0];
        if (r + 1 < cnt) a1 += row[64];
        if (r + 2 < cnt) a2 += row[128];
        if (r + 3 < cnt) a3 += row[192];
    }
    wsum[wv][lane] = (a0 + a1) + (a2 + a3);
    __syncthreads();
    if (wv == 0) {
        float tot = (wsum[0][lane] + wsum[1][lane]) + (wsum[2][lane] + wsum[3][lane]);
        float pooled = tot / fmaxf((float)cnt, 1.f);
        out[G + (size_t)g * 64 + lane] = pooled;
        float p = pooled * Wr[lane];
#pragma unroll
        for (int o = 32; o > 0; o >>= 1) p += __shfl_xor(p, o, 64);
        if (lane == 0) out[g] = p + br[0];
    }
}

extern "C" void kernel_launch(void* const* d_in, const int* in_sizes, int n_in,
                              void* d_out, int out_size, void* d_ws, size_t ws_size,
                              hipStream_t stream) {
    const float* X        = (const float*)d_in[0];
    const int*   ei       = (const int*)d_in[1];
    const int*   batch    = (const int*)d_in[2];
    const float* W1       = (const float*)d_in[3];
    const float* Ws       = (const float*)d_in[4];
    const float* att_src  = (const float*)d_in[5];
    const float* att_dst  = (const float*)d_in[6];
    const float* bias     = (const float*)d_in[7];
    const float* bn_gamma = (const float*)d_in[8];
    const float* bn_beta  = (const float*)d_in[9];
    const float* bn_mean  = (const float*)d_in[10];
    const float* bn_var   = (const float*)d_in[11];
    const float* Wr       = (const float*)d_in[12];
    const float* br       = (const float*)d_in[13];

    const int N = in_sizes[0];        // IN == 1
    const int E = in_sizes[1] / 2;
    const int G = out_size / 65;      // pred[G] + pooled[G*64]
    const int T = E + N;
    const int NB = (N + 255) >> 8;    // dst buckets (196 for N=50000; <=256)

    char* ws = (char*)d_ws;
    size_t off = 0;
    auto take = [&](size_t bytes) {
        void* p = ws + off;
        off = (off + bytes + 255) & ~(size_t)255;
        return p;
    };
    int nb = (N + 255) / 256;
    int*   counts     = (int*)take(sizeof(int) * N);
    int*   row_start  = (int*)take(sizeof(int) * (N + 1));
    int*   csr_src    = (int*)take(sizeof(int) * T);
    float* as         = (float*)take(sizeof(float) * N);
    float* ad         = (float*)take(sizeof(float) * N);
    float* h          = (float*)take(sizeof(float) * (size_t)N * 64);
    float* xa         = (float*)take(sizeof(float) * (size_t)N * 64);
    float* xb         = (float*)take(sizeof(float) * (size_t)N * 64);
    int*   gstart     = (int*)take(sizeof(int) * (G + 1));
    int*   bsum       = (int*)take(sizeof(int) * nb);
    int*   boff       = (int*)take(sizeof(int) * nb);
    int*   bkt_cursor = (int*)take(sizeof(int) * NB);
    unsigned* ebuf    = (unsigned*)h;  // alias: h is written only after phase 2
    (void)ws_size;

    const int* esrc = ei;
    const int* edst = ei + E;

    hipMemsetAsync(bkt_cursor, 0, sizeof(int) * NB, stream);

    int nbN = (N + 255) / 256;
    init_counts_kernel<<<nbN, 256, 0, stream>>>(counts, N);
    count_kernel<<<(E + 255) / 256, 256, 0, stream>>>(edst, counts, E);
    block_sum_kernel<<<nb, 256, 0, stream>>>(counts, bsum, N);
    scan_bsum_kernel<<<1, 256, 0, stream>>>(bsum, boff, nb);
    scan_final_kernel<<<nb, 256, 0, stream>>>(counts, boff, row_start, N, T);
    bucket_scatter_kernel<<<(T + CH - 1) / CH, 256, 0, stream>>>(esrc, edst, row_start,
                                                                 bkt_cursor, ebuf, E, N, NB);
    bucket_sort_kernel<<<NB, 256, 0, stream>>>(ebuf, row_start, csr_src, N);

    int wb  = (N + 3) / 4;   // aggregate: 4 waves (nodes) per 256-thread block
    int tb  = (N + 63) / 64; // transform: 64-node tiles
    layer1_kernel<<<wb, 256, 0, stream>>>(X, W1, att_src, att_dst, h, as, ad, N);
    aggregate_kernel<<<wb, 256, 0, stream>>>(h, as, ad, row_start, csr_src,
                                             bias, bn_gamma, bn_beta, bn_mean, bn_var, xa, N);
    float* xin = xa;
    float* xout = xb;
    for (int L = 1; L < 5; ++L) {
        transform_kernel<<<tb, 256, 0, stream>>>(xin, Ws + (size_t)(L - 1) * 64 * 64,
                                                 att_src + (size_t)L * 64, att_dst + (size_t)L * 64,
                                                 h, as, ad, N);
        aggregate_kernel<<<wb, 256, 0, stream>>>(h, as, ad, row_start, csr_src,
                                                 bias + (size_t)L * 64, bn_gamma + (size_t)L * 64,
                                                 bn_beta + (size_t)L * 64, bn_mean + (size_t)L * 64,
                                                 bn_var + (size_t)L * 64, xout, N);
        float* t = xin; xin = xout; xout = t;
    }

    gbounds_kernel<<<(N + 256) / 256, 256, 0, stream>>>(batch, gstart, N, G);
    pool_kernel<<<G, 256, 0, stream>>>(xin, gstart, Wr, br, (float*)d_out, G);
}

// Round 7
// 347.847 us; speedup vs baseline: 3.1064x; 1.2064x over previous
//
#include <hip/hip_runtime.h>
#include <hip/hip_fp16.h>
#include <math.h>

// ---------------------------------------------------------------------------
// GAT regression: 5x (GATConv -> ReLU -> BN) -> mean pool -> linear head.
// CSR-by-dst built on device each launch (deterministic work).
// R1: hierarchical scan. R2: register-tiled transform GEMM. R3: parallel pool.
// R4: graph bounds from sorted batch. R5: LDS-staged bucket sort CSR build.
// R6: aggregate = lane-parallel softmax + readlane-broadcast gather; h in fp16
//     (was 49us x5: ~40 VALU instr/edge serial loop + 84MB L2 fill of fp32 h).
// ---------------------------------------------------------------------------

#define CH  4096   // edges per phase-1 chunk
#define CAP 6144   // phase-2 LDS csr capacity (avg bucket ~4350)

__global__ __launch_bounds__(256) void init_counts_kernel(int* __restrict__ counts, int N) {
    int i = blockIdx.x * blockDim.x + threadIdx.x;
    if (i < N) counts[i] = 1;  // self-loop contributes 1 in-edge per node
}

__global__ __launch_bounds__(256) void count_kernel(const int* __restrict__ edst,
                                                    int* __restrict__ counts, int E) {
    int i = blockIdx.x * blockDim.x + threadIdx.x;
    if (i < E) atomicAdd(&counts[edst[i]], 1);
}

// --- hierarchical exclusive scan ----------------------------------------------
__global__ __launch_bounds__(256) void block_sum_kernel(const int* __restrict__ counts,
                                                        int* __restrict__ bsum, int N) {
    int i = blockIdx.x * 256 + threadIdx.x;
    int v = (i < N) ? counts[i] : 0;
#pragma unroll
    for (int o = 32; o > 0; o >>= 1) v += __shfl_xor(v, o, 64);
    __shared__ int wsum[4];
    if ((threadIdx.x & 63) == 0) wsum[threadIdx.x >> 6] = v;
    __syncthreads();
    if (threadIdx.x == 0) bsum[blockIdx.x] = wsum[0] + wsum[1] + wsum[2] + wsum[3];
}

__global__ __launch_bounds__(256) void scan_bsum_kernel(const int* __restrict__ bsum,
                                                        int* __restrict__ boff, int nb) {
    __shared__ int buf[256];
    int t = threadIdx.x;
    int v = (t < nb) ? bsum[t] : 0;
    buf[t] = v;
    __syncthreads();
    for (int o = 1; o < 256; o <<= 1) {
        int u = (t >= o) ? buf[t - o] : 0;
        __syncthreads();
        buf[t] += u;
        __syncthreads();
    }
    if (t < nb) boff[t] = buf[t] - v;
}

__global__ __launch_bounds__(256) void scan_final_kernel(const int* __restrict__ counts,
                                                         const int* __restrict__ boff,
                                                         int* __restrict__ row_start,
                                                         int N, int T) {
    __shared__ int buf[256];
    int t = threadIdx.x;
    int i = blockIdx.x * 256 + t;
    int v = (i < N) ? counts[i] : 0;
    buf[t] = v;
    __syncthreads();
    for (int o = 1; o < 256; o <<= 1) {
        int u = (t >= o) ? buf[t - o] : 0;
        __syncthreads();
        buf[t] += u;
        __syncthreads();
    }
    int excl = buf[t] - v + boff[blockIdx.x];
    if (i < N) row_start[i] = excl;
    if (i == N - 1) row_start[N] = T;
}
// -----------------------------------------------------------------------------

// R5 phase 1: LDS-staged bucketing. Bucket = dst>>8 (256 nodes).
__global__ __launch_bounds__(256) void bucket_scatter_kernel(const int* __restrict__ esrc,
                                                             const int* __restrict__ edst,
                                                             const int* __restrict__ row_start,
                                                             int* __restrict__ bkt_cursor,
                                                             unsigned* __restrict__ ebuf,
                                                             int E, int N, int NB) {
    __shared__ unsigned buf[CH];
    __shared__ unsigned short bkt[CH];
    __shared__ int histA[256], base[256], curB[256], gofs[256];
    int t    = threadIdx.x;
    int T    = E + N;
    int c0   = blockIdx.x * CH;
    int cend = min(c0 + CH, T);
    int M    = cend - c0;
    histA[t] = 0;
    __syncthreads();
    for (int i = c0 + t; i < cend; i += 256) {
        int d = (i < E) ? edst[i] : (i - E);
        atomicAdd(&histA[d >> 8], 1);
    }
    __syncthreads();
    int v = histA[t];
    base[t] = v;
    __syncthreads();
    for (int o = 1; o < 256; o <<= 1) {
        int u = (t >= o) ? base[t - o] : 0;
        __syncthreads();
        base[t] += u;
        __syncthreads();
    }
    int excl = base[t] - v;
    __syncthreads();
    base[t] = excl;
    curB[t] = excl;
    __syncthreads();
    if (t < NB && v > 0)
        gofs[t] = row_start[t << 8] + atomicAdd(&bkt_cursor[t], v);
    for (int i = c0 + t; i < cend; i += 256) {
        int s, d;
        if (i < E) { s = esrc[i]; d = edst[i]; }
        else       { s = i - E;   d = s; }
        int b = d >> 8;
        int r = atomicAdd(&curB[b], 1);
        buf[r] = ((unsigned)s << 8) | (unsigned)(d & 255);
        bkt[r] = (unsigned short)b;
    }
    __syncthreads();
    for (int i = t; i < M; i += 256) {
        int b = bkt[i];
        ebuf[gofs[b] + (i - base[b])] = buf[i];
    }
}

// R5 phase 2: per-bucket counting sort through LDS; coalesced final write.
__global__ __launch_bounds__(256) void bucket_sort_kernel(const unsigned* __restrict__ ebuf,
                                                          const int* __restrict__ row_start,
                                                          int* __restrict__ csr_src, int N) {
    __shared__ int cur[256];
    __shared__ int csr_lds[CAP];
    int t  = threadIdx.x;
    int n0 = blockIdx.x << 8;
    int n1 = min(n0 + 256, N);
    int rs = row_start[n0];
    int re = row_start[n1];
    int M  = re - rs;
    cur[t] = (n0 + t < n1) ? (row_start[n0 + t] - rs) : 0;
    __syncthreads();
    if (M <= CAP) {
        for (int i = t; i < M; i += 256) {
            unsigned v = ebuf[rs + i];
            int p = atomicAdd(&cur[v & 255u], 1);
            csr_lds[p] = (int)(v >> 8);
        }
        __syncthreads();
        for (int i = t; i < M; i += 256) csr_src[rs + i] = csr_lds[i];
    } else {
        for (int i = t; i < M; i += 256) {
            unsigned v = ebuf[rs + i];
            int p = atomicAdd(&cur[v & 255u], 1);
            csr_src[rs + p] = (int)(v >> 8);
        }
    }
}

// Layer 1: x is [N,1], W1 is [1,64]. h stored fp16 (consumed only by gather).
__global__ __launch_bounds__(256) void layer1_kernel(const float* __restrict__ X,
                                                     const float* __restrict__ W1,
                                                     const float* __restrict__ a_s,
                                                     const float* __restrict__ a_d,
                                                     __half* __restrict__ h16,
                                                     float* __restrict__ as,
                                                     float* __restrict__ ad, int N) {
    int lane = threadIdx.x & 63;
    int wave = threadIdx.x >> 6;
    int wpb  = blockDim.x >> 6;
    float w  = W1[lane];
    float da = w * a_s[lane];
    float db = w * a_d[lane];
#pragma unroll
    for (int o = 32; o > 0; o >>= 1) {
        da += __shfl_xor(da, o, 64);
        db += __shfl_xor(db, o, 64);
    }
    for (int n = blockIdx.x * wpb + wave; n < N; n += gridDim.x * wpb) {
        float xv = X[n];
        h16[(size_t)n * 64 + lane] = __float2half(xv * w);
        if (lane == 0) { as[n] = xv * da; ad[n] = xv * db; }
    }
}

// Layers 2..5 transform: register-tiled GEMM; h output packed fp16.
__global__ __launch_bounds__(256) void transform_kernel(const float* __restrict__ x,
                                                        const float* __restrict__ W,
                                                        const float* __restrict__ a_s,
                                                        const float* __restrict__ a_d,
                                                        __half* __restrict__ h16,
                                                        float* __restrict__ as,
                                                        float* __restrict__ ad, int N) {
    __shared__ float Wl[64 * 64];
    __shared__ float xT[64 * 68];
    int t    = threadIdx.x;
    int lane = t & 63;
    int wv   = t >> 6;
    int base = blockIdx.x * 64;

    for (int i = t; i < 64 * 64; i += 256) Wl[i] = W[i];
#pragma unroll
    for (int r = 0; r < 16; ++r) {
        int nl = wv * 16 + r;
        int n  = base + nl;
        float v = (n < N) ? x[(size_t)n * 64 + lane] : 0.f;
        xT[lane * 68 + nl] = v;
    }
    __syncthreads();

    int c0  = (t & 15) * 4;
    int nl0 = (t >> 4) * 4;
    float acc[4][4] = {{0.f}};
#pragma unroll 8
    for (int k = 0; k < 64; ++k) {
        float4 xv = *reinterpret_cast<const float4*>(&xT[k * 68 + nl0]);
        float4 wl = *reinterpret_cast<const float4*>(&Wl[k * 64 + c0]);
        acc[0][0] = fmaf(xv.x, wl.x, acc[0][0]);
        acc[0][1] = fmaf(xv.x, wl.y, acc[0][1]);
        acc[0][2] = fmaf(xv.x, wl.z, acc[0][2]);
        acc[0][3] = fmaf(xv.x, wl.w, acc[0][3]);
        acc[1][0] = fmaf(xv.y, wl.x, acc[1][0]);
        acc[1][1] = fmaf(xv.y, wl.y, acc[1][1]);
        acc[1][2] = fmaf(xv.y, wl.z, acc[1][2]);
        acc[1][3] = fmaf(xv.y, wl.w, acc[1][3]);
        acc[2][0] = fmaf(xv.z, wl.x, acc[2][0]);
        acc[2][1] = fmaf(xv.z, wl.y, acc[2][1]);
        acc[2][2] = fmaf(xv.z, wl.z, acc[2][2]);
        acc[2][3] = fmaf(xv.z, wl.w, acc[2][3]);
        acc[3][0] = fmaf(xv.w, wl.x, acc[3][0]);
        acc[3][1] = fmaf(xv.w, wl.y, acc[3][1]);
        acc[3][2] = fmaf(xv.w, wl.z, acc[3][2]);
        acc[3][3] = fmaf(xv.w, wl.w, acc[3][3]);
    }

    float4 asv = *reinterpret_cast<const float4*>(&a_s[c0]);
    float4 adv = *reinterpret_cast<const float4*>(&a_d[c0]);
#pragma unroll
    for (int i = 0; i < 4; ++i) {
        int n = base + nl0 + i;
        if (n < N) {
            union { __half2 h2[2]; uint2 u; } pk;
            pk.h2[0] = __floats2half2_rn(acc[i][0], acc[i][1]);
            pk.h2[1] = __floats2half2_rn(acc[i][2], acc[i][3]);
            *reinterpret_cast<uint2*>(&h16[(size_t)n * 64 + c0]) = pk.u;
        }
        float s1 = acc[i][0] * asv.x + acc[i][1] * asv.y + acc[i][2] * asv.z + acc[i][3] * asv.w;
        float s2 = acc[i][0] * adv.x + acc[i][1] * adv.y + acc[i][2] * adv.z + acc[i][3] * adv.w;
#pragma unroll
        for (int o = 8; o > 0; o >>= 1) {
            s1 += __shfl_xor(s1, o, 64);
            s2 += __shfl_xor(s2, o, 64);
        }
        if ((lane & 15) == 0 && n < N) { as[n] = s1; ad[n] = s2; }
    }
}

__device__ __forceinline__ float readlane_f(float v, int j) {
    return __int_as_float(__builtin_amdgcn_readlane(__float_as_int(v), j));
}

// R6 aggregate: deg<=64 fast path. Lane j owns edge j: load src + logit,
// shuffle-tree max and sum (whole softmax in registers, one step). Gather
// loop broadcasts (s_j, w_j) via v_readlane (uniform -> SGPR address math).
__global__ __launch_bounds__(256) void aggregate_kernel(const __half* __restrict__ h16,
                                                        const float* __restrict__ as,
                                                        const float* __restrict__ ad,
                                                        const int* __restrict__ row_start,
                                                        const int* __restrict__ csr_src,
                                                        const float* __restrict__ bias,
                                                        const float* __restrict__ gamma,
                                                        const float* __restrict__ beta,
                                                        const float* __restrict__ mean,
                                                        const float* __restrict__ var,
                                                        float* __restrict__ xout, int N) {
    int lane = threadIdx.x & 63;
    int wave = threadIdx.x >> 6;
    int wpb  = blockDim.x >> 6;
    float bc    = bias[lane];
    float scale = gamma[lane] * rsqrtf(var[lane] + 1e-5f);
    float shift = beta[lane] - mean[lane] * scale;
    for (int d = blockIdx.x * wpb + wave; d < N; d += gridDim.x * wpb) {
        int rs  = row_start[d], re = row_start[d + 1];
        int deg = re - rs;
        float add = ad[d];
        float acc = 0.f, z = 0.f;
        if (deg <= 64) {
            int   s = 0;
            float e = -INFINITY;
            if (lane < deg) {
                s = csr_src[rs + lane];
                e = as[s] + add;
                e = (e > 0.f) ? e : 0.2f * e;
            }
            float m = e;
#pragma unroll
            for (int o = 32; o > 0; o >>= 1) m = fmaxf(m, __shfl_xor(m, o, 64));
            float w = (lane < deg) ? __expf(e - m) : 0.f;
            z = w;
#pragma unroll
            for (int o = 32; o > 0; o >>= 1) z += __shfl_xor(z, o, 64);
            int j = 0;
            for (; j + 4 <= deg; j += 4) {
                int   s0 = __builtin_amdgcn_readlane(s, j + 0);
                int   s1 = __builtin_amdgcn_readlane(s, j + 1);
                int   s2 = __builtin_amdgcn_readlane(s, j + 2);
                int   s3 = __builtin_amdgcn_readlane(s, j + 3);
                float w0 = readlane_f(w, j + 0), w1 = readlane_f(w, j + 1);
                float w2 = readlane_f(w, j + 2), w3 = readlane_f(w, j + 3);
                float h0 = __half2float(h16[(size_t)s0 * 64 + lane]);
                float h1 = __half2float(h16[(size_t)s1 * 64 + lane]);
                float h2 = __half2float(h16[(size_t)s2 * 64 + lane]);
                float h3 = __half2float(h16[(size_t)s3 * 64 + lane]);
                acc = fmaf(h0, w0, acc);
                acc = fmaf(h1, w1, acc);
                acc = fmaf(h2, w2, acc);
                acc = fmaf(h3, w3, acc);
            }
            for (; j < deg; ++j) {
                int   sj = __builtin_amdgcn_readlane(s, j);
                float wj = readlane_f(w, j);
                acc = fmaf(__half2float(h16[(size_t)sj * 64 + lane]), wj, acc);
            }
        } else {  // rare fallback: serial over edges
            float m = -INFINITY;
            for (int j = rs + lane; j < re; j += 64) {
                int si = csr_src[j];
                float e = as[si] + add;
                e = (e > 0.f) ? e : 0.2f * e;
                m = fmaxf(m, e);
            }
#pragma unroll
            for (int o = 32; o > 0; o >>= 1) m = fmaxf(m, __shfl_xor(m, o, 64));
            for (int j = rs; j < re; ++j) {
                int si = csr_src[j];
                float e = as[si] + add;
                e = (e > 0.f) ? e : 0.2f * e;
                float w = __expf(e - m);
                z += w;
                acc = fmaf(__half2float(h16[(size_t)si * 64 + lane]), w, acc);
            }
        }
        float o = acc / z + bc;
        o = fmaxf(o, 0.f);
        xout[(size_t)d * 64 + lane] = fmaf(o, scale, shift);
    }
}

// batch is sorted -> graph g's nodes are [gstart[g], gstart[g+1]).
__global__ __launch_bounds__(256) void gbounds_kernel(const int* __restrict__ batch,
                                                      int* __restrict__ gstart, int N, int G) {
    int i = blockIdx.x * blockDim.x + threadIdx.x;
    if (i > N) return;
    if (i == 0) {
        for (int g = 0; g <= batch[0]; ++g) gstart[g] = 0;
    } else if (i == N) {
        for (int g = batch[N - 1] + 1; g <= G; ++g) gstart[g] = N;
    } else {
        int b0 = batch[i - 1], b1 = batch[i];
        for (int g = b0 + 1; g <= b1; ++g) gstart[g] = i;
    }
}

// One block (4 waves) per graph; LDS cross-wave combine; wave 0 writes head.
__global__ __launch_bounds__(256) void pool_kernel(const float* __restrict__ x,
                                                   const int* __restrict__ gstart,
                                                   const float* __restrict__ Wr,
                                                   const float* __restrict__ br,
                                                   float* __restrict__ out, int G) {
    __shared__ float wsum[4][64];
    int lane = threadIdx.x & 63;
    int wv   = threadIdx.x >> 6;
    int g    = blockIdx.x;
    if (g >= G) return;
    int s = gstart[g], cnt = gstart[g + 1] - s;
    float a0 = 0.f, a1 = 0.f, a2 = 0.f, a3 = 0.f;
    for (int r = wv * 4; r < cnt; r += 16) {
        const float* row = x + (size_t)(s + r) * 64 + lane;
        a0 += row[0];
        if (r + 1 < cnt) a1 += row[64];
        if (r + 2 < cnt) a2 += row[128];
        if (r + 3 < cnt) a3 += row[192];
    }
    wsum[wv][lane] = (a0 + a1) + (a2 + a3);
    __syncthreads();
    if (wv == 0) {
        float tot = (wsum[0][lane] + wsum[1][lane]) + (wsum[2][lane] + wsum[3][lane]);
        float pooled = tot / fmaxf((float)cnt, 1.f);
        out[G + (size_t)g * 64 + lane] = pooled;
        float p = pooled * Wr[lane];
#pragma unroll
        for (int o = 32; o > 0; o >>= 1) p += __shfl_xor(p, o, 64);
        if (lane == 0) out[g] = p + br[0];
    }
}

extern "C" void kernel_launch(void* const* d_in, const int* in_sizes, int n_in,
                              void* d_out, int out_size, void* d_ws, size_t ws_size,
                              hipStream_t stream) {
    const float* X        = (const float*)d_in[0];
    const int*   ei       = (const int*)d_in[1];
    const int*   batch    = (const int*)d_in[2];
    const float* W1       = (const float*)d_in[3];
    const float* Ws       = (const float*)d_in[4];
    const float* att_src  = (const float*)d_in[5];
    const float* att_dst  = (const float*)d_in[6];
    const float* bias     = (const float*)d_in[7];
    const float* bn_gamma = (const float*)d_in[8];
    const float* bn_beta  = (const float*)d_in[9];
    const float* bn_mean  = (const float*)d_in[10];
    const float* bn_var   = (const float*)d_in[11];
    const float* Wr       = (const float*)d_in[12];
    const float* br       = (const float*)d_in[13];

    const int N = in_sizes[0];        // IN == 1
    const int E = in_sizes[1] / 2;
    const int G = out_size / 65;      // pred[G] + pooled[G*64]
    const int T = E + N;
    const int NB = (N + 255) >> 8;    // dst buckets

    char* ws = (char*)d_ws;
    size_t off = 0;
    auto take = [&](size_t bytes) {
        void* p = ws + off;
        off = (off + bytes + 255) & ~(size_t)255;
        return p;
    };
    int nb = (N + 255) / 256;
    int*    counts     = (int*)take(sizeof(int) * N);
    int*    row_start  = (int*)take(sizeof(int) * (N + 1));
    int*    csr_src    = (int*)take(sizeof(int) * T);
    float*  as         = (float*)take(sizeof(float) * N);
    float*  ad         = (float*)take(sizeof(float) * N);
    __half* h16        = (__half*)take(sizeof(__half) * (size_t)N * 64);
    float*  xa         = (float*)take(sizeof(float) * (size_t)N * 64);
    float*  xb         = (float*)take(sizeof(float) * (size_t)N * 64);
    int*    gstart     = (int*)take(sizeof(int) * (G + 1));
    int*    bsum       = (int*)take(sizeof(int) * nb);
    int*    boff       = (int*)take(sizeof(int) * nb);
    int*    bkt_cursor = (int*)take(sizeof(int) * NB);
    unsigned* ebuf     = (unsigned*)h16;  // alias: h16 written only after phase 2 (T*4 <= N*128)
    (void)ws_size;

    const int* esrc = ei;
    const int* edst = ei + E;

    hipMemsetAsync(bkt_cursor, 0, sizeof(int) * NB, stream);

    int nbN = (N + 255) / 256;
    init_counts_kernel<<<nbN, 256, 0, stream>>>(counts, N);
    count_kernel<<<(E + 255) / 256, 256, 0, stream>>>(edst, counts, E);
    block_sum_kernel<<<nb, 256, 0, stream>>>(counts, bsum, N);
    scan_bsum_kernel<<<1, 256, 0, stream>>>(bsum, boff, nb);
    scan_final_kernel<<<nb, 256, 0, stream>>>(counts, boff, row_start, N, T);
    bucket_scatter_kernel<<<(T + CH - 1) / CH, 256, 0, stream>>>(esrc, edst, row_start,
                                                                 bkt_cursor, ebuf, E, N, NB);
    bucket_sort_kernel<<<NB, 256, 0, stream>>>(ebuf, row_start, csr_src, N);

    int wb  = (N + 3) / 4;   // aggregate: 4 waves (nodes) per 256-thread block
    int tb  = (N + 63) / 64; // transform: 64-node tiles
    layer1_kernel<<<wb, 256, 0, stream>>>(X, W1, att_src, att_dst, h16, as, ad, N);
    aggregate_kernel<<<wb, 256, 0, stream>>>(h16, as, ad, row_start, csr_src,
                                             bias, bn_gamma, bn_beta, bn_mean, bn_var, xa, N);
    float* xin = xa;
    float* xout = xb;
    for (int L = 1; L < 5; ++L) {
        transform_kernel<<<tb, 256, 0, stream>>>(xin, Ws + (size_t)(L - 1) * 64 * 64,
                                                 att_src + (size_t)L * 64, att_dst + (size_t)L * 64,
                                                 h16, as, ad, N);
        aggregate_kernel<<<wb, 256, 0, stream>>>(h16, as, ad, row_start, csr_src,
                                                 bias + (size_t)L * 64, bn_gamma + (size_t)L * 64,
                                                 bn_beta + (size_t)L * 64, bn_mean + (size_t)L * 64,
                                                 bn_var + (size_t)L * 64, xout, N);
        float* t = xin; xin = xout; xout = t;
    }

    gbounds_kernel<<<(N + 256) / 256, 256, 0, stream>>>(batch, gstart, N, G);
    pool_kernel<<<G, 256, 0, stream>>>(xin, gstart, Wr, br, (float*)d_out, G);
}

// Round 8
// 307.078 us; speedup vs baseline: 3.5188x; 1.1328x over previous
//
#include <hip/hip_runtime.h>
#include <hip/hip_fp16.h>
#include <math.h>

// ---------------------------------------------------------------------------
// GAT regression: 5x (GATConv -> ReLU -> BN) -> mean pool -> linear head.
// CSR-by-dst built on device each launch (deterministic work).
// R1: hierarchical scan. R2: register-tiled transform GEMM. R3: parallel pool.
// R4: graph bounds from sorted batch. R5: LDS-staged bucket sort CSR build.
// R6: lane-parallel softmax + readlane-broadcast gather; h in fp16.
// R7: CSR build without count/scan kernels (fixed-capacity bucket regions;
//     phase 2 derives row_start); pool self-locates via binary search.
//     19 -> 14 dispatches, removes 800K-atomic count + 2 extra edge reads.
// ---------------------------------------------------------------------------

#define CH   4096   // edges per phase-1 chunk
#define BCAP 8192   // per-bucket region capacity in ebuf (mean 4352, ~58 sigma)

// R7 phase 1: LDS-staged bucketing into fixed-capacity bucket regions.
// Bucket b region: ebuf[b*BCAP ...). bkt_cursor[b] accumulates bucket totals.
// Payload: (src<<8) | (dst&255) -- src < 2^24.
__global__ __launch_bounds__(256) void bucket_scatter_kernel(const int* __restrict__ esrc,
                                                             const int* __restrict__ edst,
                                                             int* __restrict__ bkt_cursor,
                                                             unsigned* __restrict__ ebuf,
                                                             int E, int N, int NB) {
    __shared__ unsigned buf[CH];
    __shared__ unsigned short bkt[CH];
    __shared__ int histA[256], base[256], curB[256], gofs[256];
    int t    = threadIdx.x;
    int T    = E + N;
    int c0   = blockIdx.x * CH;
    int cend = min(c0 + CH, T);
    int M    = cend - c0;
    histA[t] = 0;
    __syncthreads();
    for (int i = c0 + t; i < cend; i += 256) {
        int d = (i < E) ? edst[i] : (i - E);
        atomicAdd(&histA[d >> 8], 1);
    }
    __syncthreads();
    int v = histA[t];
    base[t] = v;
    __syncthreads();
    for (int o = 1; o < 256; o <<= 1) {
        int u = (t >= o) ? base[t - o] : 0;
        __syncthreads();
        base[t] += u;
        __syncthreads();
    }
    int excl = base[t] - v;
    __syncthreads();
    base[t] = excl;
    curB[t] = excl;
    __syncthreads();
    if (t < NB && v > 0)
        gofs[t] = t * BCAP + atomicAdd(&bkt_cursor[t], v);
    for (int i = c0 + t; i < cend; i += 256) {
        int s, d;
        if (i < E) { s = esrc[i]; d = edst[i]; }
        else       { s = i - E;   d = s; }       // self loops appended after edges
        int b = d >> 8;
        int r = atomicAdd(&curB[b], 1);
        buf[r] = ((unsigned)s << 8) | (unsigned)(d & 255);
        bkt[r] = (unsigned short)b;
    }
    __syncthreads();
    for (int i = t; i < M; i += 256) {
        int b = bkt[i];
        ebuf[gofs[b] + (i - base[b])] = buf[i];
    }
}

// R7: scan bucket totals (<=256) -> csr base per bucket; row_start[N] = T.
__global__ __launch_bounds__(256) void bkt_scan_kernel(const int* __restrict__ bkt_cursor,
                                                       int* __restrict__ bkt_base,
                                                       int* __restrict__ row_start,
                                                       int NB, int N, int T) {
    __shared__ int buf[256];
    int t = threadIdx.x;
    int v = (t < NB) ? bkt_cursor[t] : 0;
    buf[t] = v;
    __syncthreads();
    for (int o = 1; o < 256; o <<= 1) {
        int u = (t >= o) ? buf[t - o] : 0;
        __syncthreads();
        buf[t] += u;
        __syncthreads();
    }
    if (t < NB) bkt_base[t] = buf[t] - v;
    if (t == 0) row_start[N] = T;
}

// R7 phase 2: per-bucket counting sort. Pass A: per-node degree histogram in
// LDS + 256-scan -> writes row_start for its 256 nodes. Pass B: scatter into
// LDS csr; coalesced global flush.
__global__ __launch_bounds__(256) void bucket_sort_kernel(const unsigned* __restrict__ ebuf,
                                                          const int* __restrict__ bkt_cursor,
                                                          const int* __restrict__ bkt_base,
                                                          int* __restrict__ row_start,
                                                          int* __restrict__ csr_src, int N) {
    __shared__ int cnt[256], ofs[256];
    __shared__ int csr_lds[BCAP];
    int t    = threadIdx.x;
    int b    = blockIdx.x;
    int n0   = b << 8;
    int n1   = min(n0 + 256, N);
    int M    = bkt_cursor[b];
    int base = bkt_base[b];
    const unsigned* reg = ebuf + (size_t)b * BCAP;
    cnt[t] = 0;
    __syncthreads();
    for (int i = t; i < M; i += 256) atomicAdd(&cnt[reg[i] & 255u], 1);
    __syncthreads();
    int v = cnt[t];
    ofs[t] = v;
    __syncthreads();
    for (int o = 1; o < 256; o <<= 1) {
        int u = (t >= o) ? ofs[t - o] : 0;
        __syncthreads();
        ofs[t] += u;
        __syncthreads();
    }
    int excl = ofs[t] - v;
    if (n0 + t < n1) row_start[n0 + t] = base + excl;
    __syncthreads();
    cnt[t] = excl;           // reuse as scatter cursor
    __syncthreads();
    for (int i = t; i < M; i += 256) {
        unsigned e = reg[i];
        int p = atomicAdd(&cnt[e & 255u], 1);
        csr_lds[p] = (int)(e >> 8);
    }
    __syncthreads();
    for (int i = t; i < M; i += 256) csr_src[base + i] = csr_lds[i];
}

// Layer 1: x is [N,1], W1 is [1,64]. h stored fp16 (consumed only by gather).
__global__ __launch_bounds__(256) void layer1_kernel(const float* __restrict__ X,
                                                     const float* __restrict__ W1,
                                                     const float* __restrict__ a_s,
                                                     const float* __restrict__ a_d,
                                                     __half* __restrict__ h16,
                                                     float* __restrict__ as,
                                                     float* __restrict__ ad, int N) {
    int lane = threadIdx.x & 63;
    int wave = threadIdx.x >> 6;
    int wpb  = blockDim.x >> 6;
    float w  = W1[lane];
    float da = w * a_s[lane];
    float db = w * a_d[lane];
#pragma unroll
    for (int o = 32; o > 0; o >>= 1) {
        da += __shfl_xor(da, o, 64);
        db += __shfl_xor(db, o, 64);
    }
    for (int n = blockIdx.x * wpb + wave; n < N; n += gridDim.x * wpb) {
        float xv = X[n];
        h16[(size_t)n * 64 + lane] = __float2half(xv * w);
        if (lane == 0) { as[n] = xv * da; ad[n] = xv * db; }
    }
}

// Layers 2..5 transform: register-tiled GEMM; h output packed fp16.
__global__ __launch_bounds__(256) void transform_kernel(const float* __restrict__ x,
                                                        const float* __restrict__ W,
                                                        const float* __restrict__ a_s,
                                                        const float* __restrict__ a_d,
                                                        __half* __restrict__ h16,
                                                        float* __restrict__ as,
                                                        float* __restrict__ ad, int N) {
    __shared__ float Wl[64 * 64];
    __shared__ float xT[64 * 68];
    int t    = threadIdx.x;
    int lane = t & 63;
    int wv   = t >> 6;
    int base = blockIdx.x * 64;

    for (int i = t; i < 64 * 64; i += 256) Wl[i] = W[i];
#pragma unroll
    for (int r = 0; r < 16; ++r) {
        int nl = wv * 16 + r;
        int n  = base + nl;
        float v = (n < N) ? x[(size_t)n * 64 + lane] : 0.f;
        xT[lane * 68 + nl] = v;
    }
    __syncthreads();

    int c0  = (t & 15) * 4;
    int nl0 = (t >> 4) * 4;
    float acc[4][4] = {{0.f}};
#pragma unroll 8
    for (int k = 0; k < 64; ++k) {
        float4 xv = *reinterpret_cast<const float4*>(&xT[k * 68 + nl0]);
        float4 wl = *reinterpret_cast<const float4*>(&Wl[k * 64 + c0]);
        acc[0][0] = fmaf(xv.x, wl.x, acc[0][0]);
        acc[0][1] = fmaf(xv.x, wl.y, acc[0][1]);
        acc[0][2] = fmaf(xv.x, wl.z, acc[0][2]);
        acc[0][3] = fmaf(xv.x, wl.w, acc[0][3]);
        acc[1][0] = fmaf(xv.y, wl.x, acc[1][0]);
        acc[1][1] = fmaf(xv.y, wl.y, acc[1][1]);
        acc[1][2] = fmaf(xv.y, wl.z, acc[1][2]);
        acc[1][3] = fmaf(xv.y, wl.w, acc[1][3]);
        acc[2][0] = fmaf(xv.z, wl.x, acc[2][0]);
        acc[2][1] = fmaf(xv.z, wl.y, acc[2][1]);
        acc[2][2] = fmaf(xv.z, wl.z, acc[2][2]);
        acc[2][3] = fmaf(xv.z, wl.w, acc[2][3]);
        acc[3][0] = fmaf(xv.w, wl.x, acc[3][0]);
        acc[3][1] = fmaf(xv.w, wl.y, acc[3][1]);
        acc[3][2] = fmaf(xv.w, wl.z, acc[3][2]);
        acc[3][3] = fmaf(xv.w, wl.w, acc[3][3]);
    }

    float4 asv = *reinterpret_cast<const float4*>(&a_s[c0]);
    float4 adv = *reinterpret_cast<const float4*>(&a_d[c0]);
#pragma unroll
    for (int i = 0; i < 4; ++i) {
        int n = base + nl0 + i;
        if (n < N) {
            union { __half2 h2[2]; uint2 u; } pk;
            pk.h2[0] = __floats2half2_rn(acc[i][0], acc[i][1]);
            pk.h2[1] = __floats2half2_rn(acc[i][2], acc[i][3]);
            *reinterpret_cast<uint2*>(&h16[(size_t)n * 64 + c0]) = pk.u;
        }
        float s1 = acc[i][0] * asv.x + acc[i][1] * asv.y + acc[i][2] * asv.z + acc[i][3] * asv.w;
        float s2 = acc[i][0] * adv.x + acc[i][1] * adv.y + acc[i][2] * adv.z + acc[i][3] * adv.w;
#pragma unroll
        for (int o = 8; o > 0; o >>= 1) {
            s1 += __shfl_xor(s1, o, 64);
            s2 += __shfl_xor(s2, o, 64);
        }
        if ((lane & 15) == 0 && n < N) { as[n] = s1; ad[n] = s2; }
    }
}

__device__ __forceinline__ float readlane_f(float v, int j) {
    return __int_as_float(__builtin_amdgcn_readlane(__float_as_int(v), j));
}

// R6 aggregate: deg<=64 fast path. Lane j owns edge j; softmax in registers;
// gather loop broadcasts (s_j, w_j) via v_readlane.
__global__ __launch_bounds__(256) void aggregate_kernel(const __half* __restrict__ h16,
                                                        const float* __restrict__ as,
                                                        const float* __restrict__ ad,
                                                        const int* __restrict__ row_start,
                                                        const int* __restrict__ csr_src,
                                                        const float* __restrict__ bias,
                                                        const float* __restrict__ gamma,
                                                        const float* __restrict__ beta,
                                                        const float* __restrict__ mean,
                                                        const float* __restrict__ var,
                                                        float* __restrict__ xout, int N) {
    int lane = threadIdx.x & 63;
    int wave = threadIdx.x >> 6;
    int wpb  = blockDim.x >> 6;
    float bc    = bias[lane];
    float scale = gamma[lane] * rsqrtf(var[lane] + 1e-5f);
    float shift = beta[lane] - mean[lane] * scale;
    for (int d = blockIdx.x * wpb + wave; d < N; d += gridDim.x * wpb) {
        int rs  = row_start[d], re = row_start[d + 1];
        int deg = re - rs;
        float add = ad[d];
        float acc = 0.f, z = 0.f;
        if (deg <= 64) {
            int   s = 0;
            float e = -INFINITY;
            if (lane < deg) {
                s = csr_src[rs + lane];
                e = as[s] + add;
                e = (e > 0.f) ? e : 0.2f * e;
            }
            float m = e;
#pragma unroll
            for (int o = 32; o > 0; o >>= 1) m = fmaxf(m, __shfl_xor(m, o, 64));
            float w = (lane < deg) ? __expf(e - m) : 0.f;
            z = w;
#pragma unroll
            for (int o = 32; o > 0; o >>= 1) z += __shfl_xor(z, o, 64);
            int j = 0;
            for (; j + 4 <= deg; j += 4) {
                int   s0 = __builtin_amdgcn_readlane(s, j + 0);
                int   s1 = __builtin_amdgcn_readlane(s, j + 1);
                int   s2 = __builtin_amdgcn_readlane(s, j + 2);
                int   s3 = __builtin_amdgcn_readlane(s, j + 3);
                float w0 = readlane_f(w, j + 0), w1 = readlane_f(w, j + 1);
                float w2 = readlane_f(w, j + 2), w3 = readlane_f(w, j + 3);
                float h0 = __half2float(h16[(size_t)s0 * 64 + lane]);
                float h1 = __half2float(h16[(size_t)s1 * 64 + lane]);
                float h2 = __half2float(h16[(size_t)s2 * 64 + lane]);
                float h3 = __half2float(h16[(size_t)s3 * 64 + lane]);
                acc = fmaf(h0, w0, acc);
                acc = fmaf(h1, w1, acc);
                acc = fmaf(h2, w2, acc);
                acc = fmaf(h3, w3, acc);
            }
            for (; j < deg; ++j) {
                int   sj = __builtin_amdgcn_readlane(s, j);
                float wj = readlane_f(w, j);
                acc = fmaf(__half2float(h16[(size_t)sj * 64 + lane]), wj, acc);
            }
        } else {  // rare fallback: serial over edges
            float m = -INFINITY;
            for (int j = rs + lane; j < re; j += 64) {
                int si = csr_src[j];
                float e = as[si] + add;
                e = (e > 0.f) ? e : 0.2f * e;
                m = fmaxf(m, e);
            }
#pragma unroll
            for (int o = 32; o > 0; o >>= 1) m = fmaxf(m, __shfl_xor(m, o, 64));
            for (int j = rs; j < re; ++j) {
                int si = csr_src[j];
                float e = as[si] + add;
                e = (e > 0.f) ? e : 0.2f * e;
                float w = __expf(e - m);
                z += w;
                acc = fmaf(__half2float(h16[(size_t)si * 64 + lane]), w, acc);
            }
        }
        float o = acc / z + bc;
        o = fmaxf(o, 0.f);
        xout[(size_t)d * 64 + lane] = fmaf(o, scale, shift);
    }
}

// R7 pool: block g binary-searches sorted batch for its own node range
// (2 lanes, ~16 L2 loads each); 4-wave strided sum; wave 0 writes head.
__global__ __launch_bounds__(256) void pool_kernel(const float* __restrict__ x,
                                                   const int* __restrict__ batch,
                                                   const float* __restrict__ Wr,
                                                   const float* __restrict__ br,
                                                   float* __restrict__ out, int N, int G) {
    __shared__ float wsum[4][64];
    __shared__ int bounds[2];
    int t    = threadIdx.x;
    int lane = t & 63;
    int wv   = t >> 6;
    int g    = blockIdx.x;
    if (g >= G) return;
    if (t < 2) {
        int key = g + t;         // lower_bound(batch, key)
        int lo = 0, hi = N;
        while (lo < hi) {
            int mid = (lo + hi) >> 1;
            if (batch[mid] < key) lo = mid + 1; else hi = mid;
        }
        bounds[t] = lo;
    }
    __syncthreads();
    int s   = bounds[0];
    int cnt = bounds[1] - s;
    float a0 = 0.f, a1 = 0.f, a2 = 0.f, a3 = 0.f;
    for (int r = wv * 4; r < cnt; r += 16) {
        const float* row = x + (size_t)(s + r) * 64 + lane;
        a0 += row[0];
        if (r + 1 < cnt) a1 += row[64];
        if (r + 2 < cnt) a2 += row[128];
        if (r + 3 < cnt) a3 += row[192];
    }
    wsum[wv][lane] = (a0 + a1) + (a2 + a3);
    __syncthreads();
    if (wv == 0) {
        float tot = (wsum[0][lane] + wsum[1][lane]) + (wsum[2][lane] + wsum[3][lane]);
        float pooled = tot / fmaxf((float)cnt, 1.f);
        out[G + (size_t)g * 64 + lane] = pooled;
        float p = pooled * Wr[lane];
#pragma unroll
        for (int o = 32; o > 0; o >>= 1) p += __shfl_xor(p, o, 64);
        if (lane == 0) out[g] = p + br[0];
    }
}

extern "C" void kernel_launch(void* const* d_in, const int* in_sizes, int n_in,
                              void* d_out, int out_size, void* d_ws, size_t ws_size,
                              hipStream_t stream) {
    const float* X        = (const float*)d_in[0];
    const int*   ei       = (const int*)d_in[1];
    const int*   batch    = (const int*)d_in[2];
    const float* W1       = (const float*)d_in[3];
    const float* Ws       = (const float*)d_in[4];
    const float* att_src  = (const float*)d_in[5];
    const float* att_dst  = (const float*)d_in[6];
    const float* bias     = (const float*)d_in[7];
    const float* bn_gamma = (const float*)d_in[8];
    const float* bn_beta  = (const float*)d_in[9];
    const float* bn_mean  = (const float*)d_in[10];
    const float* bn_var   = (const float*)d_in[11];
    const float* Wr       = (const float*)d_in[12];
    const float* br       = (const float*)d_in[13];

    const int N = in_sizes[0];        // IN == 1
    const int E = in_sizes[1] / 2;
    const int G = out_size / 65;      // pred[G] + pooled[G*64]
    const int T = E + N;
    const int NB = (N + 255) >> 8;    // dst buckets (196 for N=50000; <=256)

    char* ws = (char*)d_ws;
    size_t off = 0;
    auto take = [&](size_t bytes) {
        void* p = ws + off;
        off = (off + bytes + 255) & ~(size_t)255;
        return p;
    };
    int*      row_start  = (int*)take(sizeof(int) * (N + 1));
    int*      csr_src    = (int*)take(sizeof(int) * T);
    float*    as         = (float*)take(sizeof(float) * N);
    float*    ad         = (float*)take(sizeof(float) * N);
    __half*   h16        = (__half*)take(sizeof(__half) * (size_t)N * 64);
    float*    xa         = (float*)take(sizeof(float) * (size_t)N * 64);
    float*    xb         = (float*)take(sizeof(float) * (size_t)N * 64);
    int*      bkt_cursor = (int*)take(sizeof(int) * NB);
    int*      bkt_base   = (int*)take(sizeof(int) * NB);
    unsigned* ebuf       = (unsigned*)take(sizeof(unsigned) * (size_t)NB * BCAP);
    (void)ws_size;

    const int* esrc = ei;
    const int* edst = ei + E;

    hipMemsetAsync(bkt_cursor, 0, sizeof(int) * NB, stream);

    bucket_scatter_kernel<<<(T + CH - 1) / CH, 256, 0, stream>>>(esrc, edst, bkt_cursor,
                                                                 ebuf, E, N, NB);
    bkt_scan_kernel<<<1, 256, 0, stream>>>(bkt_cursor, bkt_base, row_start, NB, N, T);
    bucket_sort_kernel<<<NB, 256, 0, stream>>>(ebuf, bkt_cursor, bkt_base,
                                               row_start, csr_src, N);

    int wb  = (N + 3) / 4;   // aggregate: 4 waves (nodes) per 256-thread block
    int tb  = (N + 63) / 64; // transform: 64-node tiles
    layer1_kernel<<<wb, 256, 0, stream>>>(X, W1, att_src, att_dst, h16, as, ad, N);
    aggregate_kernel<<<wb, 256, 0, stream>>>(h16, as, ad, row_start, csr_src,
                                             bias, bn_gamma, bn_beta, bn_mean, bn_var, xa, N);
    float* xin = xa;
    float* xout = xb;
    for (int L = 1; L < 5; ++L) {
        transform_kernel<<<tb, 256, 0, stream>>>(xin, Ws + (size_t)(L - 1) * 64 * 64,
                                                 att_src + (size_t)L * 64, att_dst + (size_t)L * 64,
                                                 h16, as, ad, N);
        aggregate_kernel<<<wb, 256, 0, stream>>>(h16, as, ad, row_start, csr_src,
                                                 bias + (size_t)L * 64, bn_gamma + (size_t)L * 64,
                                                 bn_beta + (size_t)L * 64, bn_mean + (size_t)L * 64,
                                                 bn_var + (size_t)L * 64, xout, N);
        float* t = xin; xin = xout; xout = t;
    }

    pool_kernel<<<G, 256, 0, stream>>>(xin, batch, Wr, br, (float*)d_out, N, G);
}

// Round 9
// 283.061 us; speedup vs baseline: 3.8174x; 1.0848x over previous
//
#include <hip/hip_runtime.h>
#include <hip/hip_fp16.h>
#include <math.h>

// ---------------------------------------------------------------------------
// GAT regression: 5x (GATConv -> ReLU -> BN) -> mean pool -> linear head.
// CSR-by-dst built on device each launch (deterministic work).
// R5/R7: LDS bucket-sort CSR build, fixed-capacity bucket regions.
// R6: lane-parallel softmax + readlane-broadcast gather; h in fp16.
// R8: layer1 fused into aggregate1 via rank-1 algebra (scalar X gather, no h);
//     node features x in fp16 end-to-end; bkt_scan folded into bucket_sort;
//     8-wide gather unroll. 13 -> 11 dispatches.
// ---------------------------------------------------------------------------

#define CH   4096   // edges per phase-1 chunk
#define BCAP 8192   // per-bucket region capacity in ebuf (mean 4352, ~58 sigma)

// Phase 1: LDS-staged bucketing into fixed-capacity bucket regions.
// Payload: (src<<8) | (dst&255) -- src < 2^24.
__global__ __launch_bounds__(256) void bucket_scatter_kernel(const int* __restrict__ esrc,
                                                             const int* __restrict__ edst,
                                                             int* __restrict__ bkt_cursor,
                                                             unsigned* __restrict__ ebuf,
                                                             int E, int N, int NB) {
    __shared__ unsigned buf[CH];
    __shared__ unsigned short bkt[CH];
    __shared__ int histA[256], base[256], curB[256], gofs[256];
    int t    = threadIdx.x;
    int T    = E + N;
    int c0   = blockIdx.x * CH;
    int cend = min(c0 + CH, T);
    int M    = cend - c0;
    histA[t] = 0;
    __syncthreads();
    for (int i = c0 + t; i < cend; i += 256) {
        int d = (i < E) ? edst[i] : (i - E);
        atomicAdd(&histA[d >> 8], 1);
    }
    __syncthreads();
    int v = histA[t];
    base[t] = v;
    __syncthreads();
    for (int o = 1; o < 256; o <<= 1) {
        int u = (t >= o) ? base[t - o] : 0;
        __syncthreads();
        base[t] += u;
        __syncthreads();
    }
    int excl = base[t] - v;
    __syncthreads();
    base[t] = excl;
    curB[t] = excl;
    __syncthreads();
    if (t < NB && v > 0)
        gofs[t] = t * BCAP + atomicAdd(&bkt_cursor[t], v);
    for (int i = c0 + t; i < cend; i += 256) {
        int s, d;
        if (i < E) { s = esrc[i]; d = edst[i]; }
        else       { s = i - E;   d = s; }       // self loops appended after edges
        int b = d >> 8;
        int r = atomicAdd(&curB[b], 1);
        buf[r] = ((unsigned)s << 8) | (unsigned)(d & 255);
        bkt[r] = (unsigned short)b;
    }
    __syncthreads();
    for (int i = t; i < M; i += 256) {
        int b = bkt[i];
        ebuf[gofs[b] + (i - base[b])] = buf[i];
    }
}

// Phase 2: per-bucket counting sort. Derives own csr base from bucket totals
// (R8: bkt_scan folded in); writes row_start for its 256 nodes; LDS scatter;
// coalesced flush. Last block writes row_start[N].
__global__ __launch_bounds__(256) void bucket_sort_kernel(const unsigned* __restrict__ ebuf,
                                                          const int* __restrict__ bkt_cursor,
                                                          int* __restrict__ row_start,
                                                          int* __restrict__ csr_src, int N, int NB) {
    __shared__ int cnt[256], ofs[256];
    __shared__ int csr_lds[BCAP];
    int t    = threadIdx.x;
    int b    = blockIdx.x;
    int n0   = b << 8;
    int n1   = min(n0 + 256, N);
    int M    = bkt_cursor[b];
    // base = sum of bucket totals before b (<=255 values, one scan)
    ofs[t] = (t < b) ? bkt_cursor[t] : 0;
    __syncthreads();
    for (int o = 1; o < 256; o <<= 1) {
        int u = (t >= o) ? ofs[t - o] : 0;
        __syncthreads();
        ofs[t] += u;
        __syncthreads();
    }
    int base = ofs[255];
    __syncthreads();
    const unsigned* reg = ebuf + (size_t)b * BCAP;
    cnt[t] = 0;
    __syncthreads();
    for (int i = t; i < M; i += 256) atomicAdd(&cnt[reg[i] & 255u], 1);
    __syncthreads();
    int v = cnt[t];
    ofs[t] = v;
    __syncthreads();
    for (int o = 1; o < 256; o <<= 1) {
        int u = (t >= o) ? ofs[t - o] : 0;
        __syncthreads();
        ofs[t] += u;
        __syncthreads();
    }
    int excl = ofs[t] - v;
    if (n0 + t < n1) row_start[n0 + t] = base + excl;
    if (b == NB - 1 && t == 0) row_start[N] = base + M;
    __syncthreads();
    cnt[t] = excl;           // reuse as scatter cursor
    __syncthreads();
    for (int i = t; i < M; i += 256) {
        unsigned e = reg[i];
        int p = atomicAdd(&cnt[e & 255u], 1);
        csr_lds[p] = (int)(e >> 8);
    }
    __syncthreads();
    for (int i = t; i < M; i += 256) csr_src[base + i] = csr_lds[i];
}

// R8 aggregate1: layer 1 fused. W1 is [1,64] (rank-1) so
// out[d] = w * (sum_s alpha_s X[s]); alpha from e = leaky(da*X[s] + db*X[d]).
// Per edge: one 4B gather of X[s]. Softmax + weighted scalar sum in registers.
__global__ __launch_bounds__(256) void aggregate1_kernel(const float* __restrict__ X,
                                                         const float* __restrict__ W1,
                                                         const float* __restrict__ a_s,
                                                         const float* __restrict__ a_d,
                                                         const int* __restrict__ row_start,
                                                         const int* __restrict__ csr_src,
                                                         const float* __restrict__ bias,
                                                         const float* __restrict__ gamma,
                                                         const float* __restrict__ beta,
                                                         const float* __restrict__ mean,
                                                         const float* __restrict__ var,
                                                         __half* __restrict__ xout, int N) {
    int lane = threadIdx.x & 63;
    int wave = threadIdx.x >> 6;
    int wpb  = blockDim.x >> 6;
    float w  = W1[lane];
    float da = w * a_s[lane];
    float db = w * a_d[lane];
#pragma unroll
    for (int o = 32; o > 0; o >>= 1) {
        da += __shfl_xor(da, o, 64);
        db += __shfl_xor(db, o, 64);
    }
    float bc    = bias[lane];
    float scale = gamma[lane] * rsqrtf(var[lane] + 1e-5f);
    float shift = beta[lane] - mean[lane] * scale;
    for (int d = blockIdx.x * wpb + wave; d < N; d += gridDim.x * wpb) {
        int rs  = row_start[d], re = row_start[d + 1];
        int deg = re - rs;
        float add = db * X[d];
        float S, z;
        if (deg <= 64) {
            float xs = 0.f, e = -INFINITY;
            if (lane < deg) {
                xs = X[csr_src[rs + lane]];
                e  = da * xs + add;
                e  = (e > 0.f) ? e : 0.2f * e;
            }
            float m = e;
#pragma unroll
            for (int o = 32; o > 0; o >>= 1) m = fmaxf(m, __shfl_xor(m, o, 64));
            float wj = (lane < deg) ? __expf(e - m) : 0.f;
            z = wj;
            S = wj * xs;
#pragma unroll
            for (int o = 32; o > 0; o >>= 1) {
                z += __shfl_xor(z, o, 64);
                S += __shfl_xor(S, o, 64);
            }
        } else {
            float m = -INFINITY;
            for (int j = rs + lane; j < re; j += 64) {
                float e = da * X[csr_src[j]] + add;
                e = (e > 0.f) ? e : 0.2f * e;
                m = fmaxf(m, e);
            }
#pragma unroll
            for (int o = 32; o > 0; o >>= 1) m = fmaxf(m, __shfl_xor(m, o, 64));
            z = 0.f; S = 0.f;
            for (int j = rs + lane; j < re; j += 64) {
                float xs = X[csr_src[j]];
                float e  = da * xs + add;
                e = (e > 0.f) ? e : 0.2f * e;
                float wj = __expf(e - m);
                z += wj;
                S += wj * xs;
            }
#pragma unroll
            for (int o = 32; o > 0; o >>= 1) {
                z += __shfl_xor(z, o, 64);
                S += __shfl_xor(S, o, 64);
            }
        }
        float o = w * (S / z) + bc;
        o = fmaxf(o, 0.f);
        xout[(size_t)d * 64 + lane] = __float2half(fmaf(o, scale, shift));
    }
}

// Layers 2..5 transform: register-tiled GEMM; x in fp16, math fp32; h out fp16.
__global__ __launch_bounds__(256) void transform_kernel(const __half* __restrict__ x16,
                                                        const float* __restrict__ W,
                                                        const float* __restrict__ a_s,
                                                        const float* __restrict__ a_d,
                                                        __half* __restrict__ h16,
                                                        float* __restrict__ as,
                                                        float* __restrict__ ad, int N) {
    __shared__ float Wl[64 * 64];
    __shared__ float xT[64 * 68];
    int t    = threadIdx.x;
    int lane = t & 63;
    int wv   = t >> 6;
    int base = blockIdx.x * 64;

    for (int i = t; i < 64 * 64; i += 256) Wl[i] = W[i];
#pragma unroll
    for (int r = 0; r < 16; ++r) {
        int nl = wv * 16 + r;
        int n  = base + nl;
        float v = (n < N) ? __half2float(x16[(size_t)n * 64 + lane]) : 0.f;
        xT[lane * 68 + nl] = v;
    }
    __syncthreads();

    int c0  = (t & 15) * 4;
    int nl0 = (t >> 4) * 4;
    float acc[4][4] = {{0.f}};
#pragma unroll 8
    for (int k = 0; k < 64; ++k) {
        float4 xv = *reinterpret_cast<const float4*>(&xT[k * 68 + nl0]);
        float4 wl = *reinterpret_cast<const float4*>(&Wl[k * 64 + c0]);
        acc[0][0] = fmaf(xv.x, wl.x, acc[0][0]);
        acc[0][1] = fmaf(xv.x, wl.y, acc[0][1]);
        acc[0][2] = fmaf(xv.x, wl.z, acc[0][2]);
        acc[0][3] = fmaf(xv.x, wl.w, acc[0][3]);
        acc[1][0] = fmaf(xv.y, wl.x, acc[1][0]);
        acc[1][1] = fmaf(xv.y, wl.y, acc[1][1]);
        acc[1][2] = fmaf(xv.y, wl.z, acc[1][2]);
        acc[1][3] = fmaf(xv.y, wl.w, acc[1][3]);
        acc[2][0] = fmaf(xv.z, wl.x, acc[2][0]);
        acc[2][1] = fmaf(xv.z, wl.y, acc[2][1]);
        acc[2][2] = fmaf(xv.z, wl.z, acc[2][2]);
        acc[2][3] = fmaf(xv.z, wl.w, acc[2][3]);
        acc[3][0] = fmaf(xv.w, wl.x, acc[3][0]);
        acc[3][1] = fmaf(xv.w, wl.y, acc[3][1]);
        acc[3][2] = fmaf(xv.w, wl.z, acc[3][2]);
        acc[3][3] = fmaf(xv.w, wl.w, acc[3][3]);
    }

    float4 asv = *reinterpret_cast<const float4*>(&a_s[c0]);
    float4 adv = *reinterpret_cast<const float4*>(&a_d[c0]);
#pragma unroll
    for (int i = 0; i < 4; ++i) {
        int n = base + nl0 + i;
        if (n < N) {
            union { __half2 h2[2]; uint2 u; } pk;
            pk.h2[0] = __floats2half2_rn(acc[i][0], acc[i][1]);
            pk.h2[1] = __floats2half2_rn(acc[i][2], acc[i][3]);
            *reinterpret_cast<uint2*>(&h16[(size_t)n * 64 + c0]) = pk.u;
        }
        float s1 = acc[i][0] * asv.x + acc[i][1] * asv.y + acc[i][2] * asv.z + acc[i][3] * asv.w;
        float s2 = acc[i][0] * adv.x + acc[i][1] * adv.y + acc[i][2] * adv.z + acc[i][3] * adv.w;
#pragma unroll
        for (int o = 8; o > 0; o >>= 1) {
            s1 += __shfl_xor(s1, o, 64);
            s2 += __shfl_xor(s2, o, 64);
        }
        if ((lane & 15) == 0 && n < N) { as[n] = s1; ad[n] = s2; }
    }
}

__device__ __forceinline__ float readlane_f(float v, int j) {
    return __int_as_float(__builtin_amdgcn_readlane(__float_as_int(v), j));
}

// Aggregate layers 2..5: lane-parallel softmax; readlane-broadcast gather of
// fp16 h rows, 8-wide unrolled; fused bias+ReLU+BN; xout fp16.
__global__ __launch_bounds__(256) void aggregate_kernel(const __half* __restrict__ h16,
                                                        const float* __restrict__ as,
                                                        const float* __restrict__ ad,
                                                        const int* __restrict__ row_start,
                                                        const int* __restrict__ csr_src,
                                                        const float* __restrict__ bias,
                                                        const float* __restrict__ gamma,
                                                        const float* __restrict__ beta,
                                                        const float* __restrict__ mean,
                                                        const float* __restrict__ var,
                                                        __half* __restrict__ xout, int N) {
    int lane = threadIdx.x & 63;
    int wave = threadIdx.x >> 6;
    int wpb  = blockDim.x >> 6;
    float bc    = bias[lane];
    float scale = gamma[lane] * rsqrtf(var[lane] + 1e-5f);
    float shift = beta[lane] - mean[lane] * scale;
    for (int d = blockIdx.x * wpb + wave; d < N; d += gridDim.x * wpb) {
        int rs  = row_start[d], re = row_start[d + 1];
        int deg = re - rs;
        float add = ad[d];
        float acc = 0.f, z = 0.f;
        if (deg <= 64) {
            int   s = 0;
            float e = -INFINITY;
            if (lane < deg) {
                s = csr_src[rs + lane];
                e = as[s] + add;
                e = (e > 0.f) ? e : 0.2f * e;
            }
            float m = e;
#pragma unroll
            for (int o = 32; o > 0; o >>= 1) m = fmaxf(m, __shfl_xor(m, o, 64));
            float w = (lane < deg) ? __expf(e - m) : 0.f;
            z = w;
#pragma unroll
            for (int o = 32; o > 0; o >>= 1) z += __shfl_xor(z, o, 64);
            int j = 0;
            for (; j + 8 <= deg; j += 8) {
                int   s0 = __builtin_amdgcn_readlane(s, j + 0);
                int   s1 = __builtin_amdgcn_readlane(s, j + 1);
                int   s2 = __builtin_amdgcn_readlane(s, j + 2);
                int   s3 = __builtin_amdgcn_readlane(s, j + 3);
                int   s4 = __builtin_amdgcn_readlane(s, j + 4);
                int   s5 = __builtin_amdgcn_readlane(s, j + 5);
                int   s6 = __builtin_amdgcn_readlane(s, j + 6);
                int   s7 = __builtin_amdgcn_readlane(s, j + 7);
                float h0 = __half2float(h16[(size_t)s0 * 64 + lane]);
                float h1 = __half2float(h16[(size_t)s1 * 64 + lane]);
                float h2 = __half2float(h16[(size_t)s2 * 64 + lane]);
                float h3 = __half2float(h16[(size_t)s3 * 64 + lane]);
                float h4 = __half2float(h16[(size_t)s4 * 64 + lane]);
                float h5 = __half2float(h16[(size_t)s5 * 64 + lane]);
                float h6 = __half2float(h16[(size_t)s6 * 64 + lane]);
                float h7 = __half2float(h16[(size_t)s7 * 64 + lane]);
                acc = fmaf(h0, readlane_f(w, j + 0), acc);
                acc = fmaf(h1, readlane_f(w, j + 1), acc);
                acc = fmaf(h2, readlane_f(w, j + 2), acc);
                acc = fmaf(h3, readlane_f(w, j + 3), acc);
                acc = fmaf(h4, readlane_f(w, j + 4), acc);
                acc = fmaf(h5, readlane_f(w, j + 5), acc);
                acc = fmaf(h6, readlane_f(w, j + 6), acc);
                acc = fmaf(h7, readlane_f(w, j + 7), acc);
            }
            for (; j < deg; ++j) {
                int   sj = __builtin_amdgcn_readlane(s, j);
                float wj = readlane_f(w, j);
                acc = fmaf(__half2float(h16[(size_t)sj * 64 + lane]), wj, acc);
            }
        } else {  // rare fallback: serial over edges
            float m = -INFINITY;
            for (int j = rs + lane; j < re; j += 64) {
                int si = csr_src[j];
                float e = as[si] + add;
                e = (e > 0.f) ? e : 0.2f * e;
                m = fmaxf(m, e);
            }
#pragma unroll
            for (int o = 32; o > 0; o >>= 1) m = fmaxf(m, __shfl_xor(m, o, 64));
            for (int j = rs; j < re; ++j) {
                int si = csr_src[j];
                float e = as[si] + add;
                e = (e > 0.f) ? e : 0.2f * e;
                float w = __expf(e - m);
                z += w;
                acc = fmaf(__half2float(h16[(size_t)si * 64 + lane]), w, acc);
            }
        }
        float o = acc / z + bc;
        o = fmaxf(o, 0.f);
        xout[(size_t)d * 64 + lane] = __float2half(fmaf(o, scale, shift));
    }
}

// Pool: block g binary-searches sorted batch for its node range; x is fp16.
__global__ __launch_bounds__(256) void pool_kernel(const __half* __restrict__ x16,
                                                   const int* __restrict__ batch,
                                                   const float* __restrict__ Wr,
                                                   const float* __restrict__ br,
                                                   float* __restrict__ out, int N, int G) {
    __shared__ float wsum[4][64];
    __shared__ int bounds[2];
    int t    = threadIdx.x;
    int lane = t & 63;
    int wv   = t >> 6;
    int g    = blockIdx.x;
    if (g >= G) return;
    if (t < 2) {
        int key = g + t;         // lower_bound(batch, key)
        int lo = 0, hi = N;
        while (lo < hi) {
            int mid = (lo + hi) >> 1;
            if (batch[mid] < key) lo = mid + 1; else hi = mid;
        }
        bounds[t] = lo;
    }
    __syncthreads();
    int s   = bounds[0];
    int cnt = bounds[1] - s;
    float a0 = 0.f, a1 = 0.f, a2 = 0.f, a3 = 0.f;
    for (int r = wv * 4; r < cnt; r += 16) {
        const __half* row = x16 + (size_t)(s + r) * 64 + lane;
        a0 += __half2float(row[0]);
        if (r + 1 < cnt) a1 += __half2float(row[64]);
        if (r + 2 < cnt) a2 += __half2float(row[128]);
        if (r + 3 < cnt) a3 += __half2float(row[192]);
    }
    wsum[wv][lane] = (a0 + a1) + (a2 + a3);
    __syncthreads();
    if (wv == 0) {
        float tot = (wsum[0][lane] + wsum[1][lane]) + (wsum[2][lane] + wsum[3][lane]);
        float pooled = tot / fmaxf((float)cnt, 1.f);
        out[G + (size_t)g * 64 + lane] = pooled;
        float p = pooled * Wr[lane];
#pragma unroll
        for (int o = 32; o > 0; o >>= 1) p += __shfl_xor(p, o, 64);
        if (lane == 0) out[g] = p + br[0];
    }
}

extern "C" void kernel_launch(void* const* d_in, const int* in_sizes, int n_in,
                              void* d_out, int out_size, void* d_ws, size_t ws_size,
                              hipStream_t stream) {
    const float* X        = (const float*)d_in[0];
    const int*   ei       = (const int*)d_in[1];
    const int*   batch    = (const int*)d_in[2];
    const float* W1       = (const float*)d_in[3];
    const float* Ws       = (const float*)d_in[4];
    const float* att_src  = (const float*)d_in[5];
    const float* att_dst  = (const float*)d_in[6];
    const float* bias     = (const float*)d_in[7];
    const float* bn_gamma = (const float*)d_in[8];
    const float* bn_beta  = (const float*)d_in[9];
    const float* bn_mean  = (const float*)d_in[10];
    const float* bn_var   = (const float*)d_in[11];
    const float* Wr       = (const float*)d_in[12];
    const float* br       = (const float*)d_in[13];

    const int N = in_sizes[0];        // IN == 1
    const int E = in_sizes[1] / 2;
    const int G = out_size / 65;      // pred[G] + pooled[G*64]
    const int T = E + N;
    const int NB = (N + 255) >> 8;    // dst buckets (196 for N=50000; <=256)

    char* ws = (char*)d_ws;
    size_t off = 0;
    auto take = [&](size_t bytes) {
        void* p = ws + off;
        off = (off + bytes + 255) & ~(size_t)255;
        return p;
    };
    int*      row_start  = (int*)take(sizeof(int) * (N + 1));
    int*      csr_src    = (int*)take(sizeof(int) * T);
    float*    as         = (float*)take(sizeof(float) * N);
    float*    ad         = (float*)take(sizeof(float) * N);
    __half*   h16        = (__half*)take(sizeof(__half) * (size_t)N * 64);
    __half*   xa         = (__half*)take(sizeof(__half) * (size_t)N * 64);
    __half*   xb         = (__half*)take(sizeof(__half) * (size_t)N * 64);
    int*      bkt_cursor = (int*)take(sizeof(int) * NB);
    unsigned* ebuf       = (unsigned*)take(sizeof(unsigned) * (size_t)NB * BCAP);
    (void)ws_size;

    const int* esrc = ei;
    const int* edst = ei + E;

    hipMemsetAsync(bkt_cursor, 0, sizeof(int) * NB, stream);

    bucket_scatter_kernel<<<(T + CH - 1) / CH, 256, 0, stream>>>(esrc, edst, bkt_cursor,
                                                                 ebuf, E, N, NB);
    bucket_sort_kernel<<<NB, 256, 0, stream>>>(ebuf, bkt_cursor, row_start, csr_src, N, NB);

    int wb  = (N + 3) / 4;   // aggregate: 4 waves (nodes) per 256-thread block
    int tb  = (N + 63) / 64; // transform: 64-node tiles
    aggregate1_kernel<<<wb, 256, 0, stream>>>(X, W1, att_src, att_dst, row_start, csr_src,
                                              bias, bn_gamma, bn_beta, bn_mean, bn_var, xa, N);
    __half* xin = xa;
    __half* xout = xb;
    for (int L = 1; L < 5; ++L) {
        transform_kernel<<<tb, 256, 0, stream>>>(xin, Ws + (size_t)(L - 1) * 64 * 64,
                                                 att_src + (size_t)L * 64, att_dst + (size_t)L * 64,
                                                 h16, as, ad, N);
        aggregate_kernel<<<wb, 256, 0, stream>>>(h16, as, ad, row_start, csr_src,
                                                 bias + (size_t)L * 64, bn_gamma + (size_t)L * 64,
                                                 bn_beta + (size_t)L * 64, bn_mean + (size_t)L * 64,
                                                 bn_var + (size_t)L * 64, xout, N);
        __half* t = xin; xin = xout; xout = t;
    }

    pool_kernel<<<G, 256, 0, stream>>>(xin, batch, Wr, br, (float*)d_out, N, G);
}